// Round 1
// 582.287 us; speedup vs baseline: 1.1019x; 1.1019x over previous
//
#include <hip/hip_runtime.h>
#include <math.h>

// (B,S,D,H,HD) = (2,2048,2048,16,128)
#define Bc   2
#define Sc   2048
#define Dc   2048
#define Hc   16
#define HDc  128
#define BSc  4096
#define HHDc 2048

typedef __bf16 bf16_t;
typedef __bf16 bf16x8 __attribute__((ext_vector_type(8)));
typedef __bf16 bf16x4 __attribute__((ext_vector_type(4)));
typedef float  f32x4  __attribute__((ext_vector_type(4)));

#define AS1(p) ((const __attribute__((address_space(1))) void*)(p))
#define AS3(p) ((__attribute__((address_space(3))) void*)(p))

#define MFMA16(a,b,c) __builtin_amdgcn_mfma_f32_16x16x32_bf16((a),(b),(c),0,0,0)

// ---------------------------------------------------------------------------
// x: fp32 -> bf16 (same layout)  [verified]
// ---------------------------------------------------------------------------
__global__ void convert_x(const float* __restrict__ x, bf16_t* __restrict__ xb)
{
    const size_t i = ((size_t)blockIdx.x * 256 + threadIdx.x) * 4;
    float4 v = *(const float4*)&x[i];
    bf16x4 o; o[0]=(bf16_t)v.x; o[1]=(bf16_t)v.y; o[2]=(bf16_t)v.z; o[3]=(bf16_t)v.w;
    *(bf16x4*)&xb[i] = o;
}

// ---------------------------------------------------------------------------
// fp32 -> bf16 with scale, same layout  [R5-verified]
// ---------------------------------------------------------------------------
__global__ void scale_cast(const float* __restrict__ in, bf16_t* __restrict__ out,
                           float s)
{
    const size_t i = ((size_t)blockIdx.x * 256 + threadIdx.x) * 4;
    float4 v = *(const float4*)&in[i];
    bf16x4 o; o[0]=(bf16_t)(v.x*s); o[1]=(bf16_t)(v.y*s);
    o[2]=(bf16_t)(v.z*s); o[3]=(bf16_t)(v.w*s);
    *(bf16x4*)&out[i] = o;
}

// ---------------------------------------------------------------------------
// W [K=2048][N=2048] fp32 -> W^T [N][K] bf16  [verified]
// ---------------------------------------------------------------------------
__global__ __launch_bounds__(256) void transpose_w(const float* __restrict__ in,
                                                   bf16_t* __restrict__ out)
{
    __shared__ float T[64][65];
    const int t = threadIdx.x;
    const int r0 = blockIdx.y * 64, c0 = blockIdx.x * 64;
    #pragma unroll
    for (int i = 0; i < 4; ++i) {
        int row = i * 16 + (t >> 4);
        int c4  = (t & 15) * 4;
        float4 v = *(const float4*)&in[(size_t)(r0 + row) * 2048 + c0 + c4];
        T[row][c4] = v.x; T[row][c4+1] = v.y; T[row][c4+2] = v.z; T[row][c4+3] = v.w;
    }
    __syncthreads();
    #pragma unroll
    for (int i = 0; i < 4; ++i) {
        int orow = i * 16 + (t >> 4);
        int c4   = (t & 15) * 4;
        bf16x4 o;
        #pragma unroll
        for (int j = 0; j < 4; ++j) o[j] = (bf16_t)T[c4 + j][orow];
        *(bf16x4*)&out[(size_t)(c0 + orow) * 2048 + r0 + c4] = o;
    }
}

// ---------------------------------------------------------------------------
// fp32 V [b*S+s][h*128+hd] -> bf16 V^T [bh][hd][s]  (transpose_w pattern)
// ---------------------------------------------------------------------------
__global__ __launch_bounds__(256) void prep_vt(const float* __restrict__ V,
                                               bf16_t* __restrict__ Vt)
{
    __shared__ float T[64][65];
    const int t = threadIdx.x;
    const int s0 = blockIdx.x * 64;
    const int c0 = blockIdx.y * 64;          // hd tile (0 or 64)
    const int bh = blockIdx.z;
    const int b = bh >> 4, h = bh & 15;
    #pragma unroll
    for (int i = 0; i < 4; ++i) {
        int row = i * 16 + (t >> 4);         // s-local
        int c4  = (t & 15) * 4;              // hd-local
        float4 v = *(const float4*)&V[((size_t)(b * Sc + s0 + row)) * HHDc + h * HDc + c0 + c4];
        T[row][c4] = v.x; T[row][c4+1] = v.y; T[row][c4+2] = v.z; T[row][c4+3] = v.w;
    }
    __syncthreads();
    #pragma unroll
    for (int i = 0; i < 4; ++i) {
        int orow = i * 16 + (t >> 4);        // hd-local
        int c4   = (t & 15) * 4;             // s-local
        bf16x4 o;
        #pragma unroll
        for (int j = 0; j < 4; ++j) o[j] = (bf16_t)T[c4 + j][orow];
        *(bf16x4*)&Vt[((size_t)bh * HDc + c0 + orow) * Sc + s0 + c4] = o;
    }
}

// ---------------------------------------------------------------------------
// GEMM: C[4096][2048] = A * Bt^T, bf16 in fp32 out  [verified]
// ---------------------------------------------------------------------------
__global__ __launch_bounds__(256) void gemm_bt(const bf16_t* __restrict__ A,
                                               const bf16_t* __restrict__ Bt,
                                               float* __restrict__ C)
{
    __shared__ bf16_t As[128 * 64];
    __shared__ bf16_t Bs[128 * 64];
    const int t = threadIdx.x;
    const int w = t >> 6, l = t & 63;
    const int wm = w >> 1, wn = w & 1;
    const int lane15 = l & 15, quad = l >> 4;
    const int m0 = blockIdx.y * 128, n0 = blockIdx.x * 128;

    f32x4 acc[4][4];
    #pragma unroll
    for (int i = 0; i < 4; ++i)
        #pragma unroll
        for (int j = 0; j < 4; ++j)
            #pragma unroll
            for (int c = 0; c < 4; ++c) acc[i][j][c] = 0.f;

    const int srow = w * 8 + (l >> 3);
    const int sch  = l & 7;

    for (int k0 = 0; k0 < 2048; k0 += 64) {
        __syncthreads();
        #pragma unroll
        for (int p = 0; p < 4; ++p) {
            __builtin_amdgcn_global_load_lds(
                AS1(A + (size_t)(m0 + p * 32 + srow) * 2048 + k0 + sch * 8),
                AS3(&As[(p * 32 + w * 8) * 64]), 16, 0, 0);
            __builtin_amdgcn_global_load_lds(
                AS1(Bt + (size_t)(n0 + p * 32 + srow) * 2048 + k0 + sch * 8),
                AS3(&Bs[(p * 32 + w * 8) * 64]), 16, 0, 0);
        }
        __syncthreads();
        #pragma unroll
        for (int ks = 0; ks < 2; ++ks) {
            const int rc = (ks * 4 + quad) * 8;
            bf16x8 a[4], b[4];
            #pragma unroll
            for (int mt = 0; mt < 4; ++mt)
                a[mt] = *(const bf16x8*)&As[(wm * 64 + mt * 16 + lane15) * 64 + rc];
            #pragma unroll
            for (int nt = 0; nt < 4; ++nt)
                b[nt] = *(const bf16x8*)&Bs[(wn * 64 + nt * 16 + lane15) * 64 + rc];
            #pragma unroll
            for (int mt = 0; mt < 4; ++mt)
                #pragma unroll
                for (int nt = 0; nt < 4; ++nt)
                    acc[mt][nt] = MFMA16(a[mt], b[nt], acc[mt][nt]);
        }
    }

    #pragma unroll
    for (int mt = 0; mt < 4; ++mt)
        #pragma unroll
        for (int nt = 0; nt < 4; ++nt)
            #pragma unroll
            for (int r = 0; r < 4; ++r) {
                const int gm = m0 + wm * 64 + mt * 16 + quad * 4 + r;
                const int gn = n0 + wn * 64 + nt * 16 + lane15;
                C[(size_t)gm * 2048 + gn] = acc[mt][nt][r];
            }
}

// ---------------------------------------------------------------------------
// RoPE in-place on fp32 Q,K  [verified]
// ---------------------------------------------------------------------------
__global__ void rope_k(float* __restrict__ Q, float* __restrict__ K)
{
    const int idx  = blockIdx.x * blockDim.x + threadIdx.x;
    const int j    = idx & 63;
    const int h    = (idx >> 6) & (Hc - 1);
    const int sabs = idx >> 10;
    const int s    = sabs & (Sc - 1);

    const float freq = expf(-(float)j * 0.14391156514261520f);
    const float ang  = (float)s * freq;
    float sn, cs;
    sincosf(ang, &sn, &cs);

    const size_t base = (size_t)sabs * HHDc + (size_t)h * HDc + j;
    float q1 = Q[base], q2 = Q[base + 64];
    Q[base]      = q1 * cs - q2 * sn;
    Q[base + 64] = q2 * cs + q1 * sn;
    float k1 = K[base], k2 = K[base + 64];
    K[base]      = k1 * cs - k2 * sn;
    K[base + 64] = k2 * cs + k1 * sn;
}

// ---------------------------------------------------------------------------
// attn_v3: attn_v2 + XOR-swizzled Qs/Ks/Vts (guide G4 + rule #21).
// global_load_lds writes linearly, so the swizzle is applied as
// inverse-swizzled per-lane GLOBAL source column + swizzled ds_read column:
//   LDS[row][cp] holds global[row][cp ^ ((row&7)*8)]   (elements, bf16)
// Read of logical col rc therefore uses LDS col rc ^ ((row&7)*8).
// At read time row&7 == lane15&7 for all three buffers (row = k*16 + lane15).
// Softmax phases unchanged (R5-verified); Ps/Ss pitches already conflict-ok.
// ---------------------------------------------------------------------------
__global__ __launch_bounds__(256) void attn_v3(const bf16_t* __restrict__ Q,
                                               const bf16_t* __restrict__ K,
                                               const bf16_t* __restrict__ Vt,
                                               bf16_t* __restrict__ CTX)
{
    __shared__ bf16_t Qs[128 * 128];   // [q_local][hd]   (col-swizzled)
    __shared__ bf16_t Ks[64 * 128];    // [k_local][hd]   (col-swizzled)
    __shared__ bf16_t Vts[128 * 64];   // [hd][key_local] (col-swizzled)
    __shared__ float  Ss[128][65];     // fp32 scores (softmax working array)
    __shared__ bf16_t Ps[128 * 72];    // bf16 P for MFMA PV (144B rows, 2-way banks)
    __shared__ float  Mrow[128], Lrow[128], Arow[128];
    __shared__ float  Mpart[128][2], Lpart[128][2];

    const int t = threadIdx.x, w = t >> 6, l = t & 63;
    const int lane15 = l & 15, quad = l >> 4;
    const int swr = (lane15 & 7) * 8;          // read-side column swizzle
    const int q0 = blockIdx.x * 128;
    const int b = blockIdx.y >> 4, h = blockIdx.y & 15;
    const size_t qbase = ((size_t)(b * Sc + q0)) * HHDc + h * HDc;
    const size_t vtb   = (size_t)blockIdx.y * HDc * Sc;

    // stage Q tile: linear LDS dest, inverse-swizzled global source column
    {
        const int srow = w * 4 + (l >> 4);
        const int swq  = (srow & 7) * 8;       // row&7 of absolute row (p*16 ≡ 0 mod 8)
        const int gcol = (lane15 * 8) ^ swq;
        #pragma unroll
        for (int p = 0; p < 8; ++p)
            __builtin_amdgcn_global_load_lds(
                AS1(Q + qbase + (size_t)(p * 16 + srow) * HHDc + gcol),
                AS3(&Qs[(p * 16 + w * 4) * 128]), 16, 0, 0);
    }
    if (t < 128) { Mrow[t] = -INFINITY; Lrow[t] = 0.f; }

    f32x4 O[8][2];      // PV acc: O[ht][qt], hd=ht*16+quad*4+c, q=qt*16+lane15 (wave-local)
    #pragma unroll
    for (int i = 0; i < 8; ++i)
        #pragma unroll
        for (int j = 0; j < 2; ++j)
            #pragma unroll
            for (int c = 0; c < 4; ++c) O[i][j][c] = 0.f;

    for (int kt = 0; kt < Sc / 64; ++kt) {
        __syncthreads();   // protect Ks/Vts/Ps restage vs prev iteration reads
        const size_t kbase = ((size_t)(b * Sc + kt * 64)) * HHDc + h * HDc;
        {   // stage K (bf16): rows=keys, hd contiguous; source col swizzled
            const int srow = w * 4 + (l >> 4);
            const int swk  = (srow & 7) * 8;
            const int gcol = (lane15 * 8) ^ swk;
            #pragma unroll
            for (int p = 0; p < 4; ++p)
                __builtin_amdgcn_global_load_lds(
                    AS1(K + kbase + (size_t)(p * 16 + srow) * HHDc + gcol),
                    AS3(&Ks[(p * 16 + w * 4) * 128]), 16, 0, 0);
        }
        {   // stage Vt (bf16): rows=hd, keys contiguous; source col swizzled
            const int vrow = w * 8 + (l >> 3);
            const int swv  = (vrow & 7) * 8;   // == ((l>>3)&7)*8
            const int gcol = ((l & 7) * 8) ^ swv;
            #pragma unroll
            for (int p = 0; p < 4; ++p)
                __builtin_amdgcn_global_load_lds(
                    AS1(Vt + vtb + (size_t)(p * 32 + vrow) * Sc + kt * 64 + gcol),
                    AS3(&Vts[(p * 32 + w * 8) * 64]), 16, 0, 0);
        }
        __syncthreads();

        // ---- MFMA QK^T: wave w owns q-rows w*32..w*32+31, all 64 keys ----
        f32x4 sc[2][4];
        #pragma unroll
        for (int i = 0; i < 2; ++i)
            #pragma unroll
            for (int j = 0; j < 4; ++j)
                #pragma unroll
                for (int c = 0; c < 4; ++c) sc[i][j][c] = 0.f;
        #pragma unroll
        for (int ks = 0; ks < 4; ++ks) {
            const int rc = ((ks * 4 + quad) * 8) ^ swr;   // swizzled column
            bf16x8 aq[2], bk[4];
            #pragma unroll
            for (int mt = 0; mt < 2; ++mt)
                aq[mt] = *(const bf16x8*)&Qs[(w * 32 + mt * 16 + lane15) * 128 + rc];
            #pragma unroll
            for (int nt = 0; nt < 4; ++nt)
                bk[nt] = *(const bf16x8*)&Ks[(nt * 16 + lane15) * 128 + rc];
            #pragma unroll
            for (int mt = 0; mt < 2; ++mt)
                #pragma unroll
                for (int nt = 0; nt < 4; ++nt)
                    sc[mt][nt] = MFMA16(aq[mt], bk[nt], sc[mt][nt]);
        }
        // scatter scores (R5-verified C/D map: row=quad*4+r -> q, col=lane15 -> key)
        #pragma unroll
        for (int mt = 0; mt < 2; ++mt)
            #pragma unroll
            for (int nt = 0; nt < 4; ++nt)
                #pragma unroll
                for (int r = 0; r < 4; ++r)
                    Ss[w * 32 + mt * 16 + quad * 4 + r][nt * 16 + lane15] = sc[mt][nt][r];
        __syncthreads();

        // ---- R5-verified LDS online softmax ----
        {
            int r = t >> 1, sg = t & 1;
            float mx = -INFINITY;
            #pragma unroll
            for (int x = 0; x < 32; ++x) mx = fmaxf(mx, Ss[r][sg * 32 + x]);
            Mpart[r][sg] = mx;
        }
        __syncthreads();
        if (t < 128) {
            float mt_ = fmaxf(Mpart[t][0], Mpart[t][1]);
            float mo = Mrow[t];
            float mn = fmaxf(mo, mt_);
            Arow[t] = __expf(mo - mn);
            Mrow[t] = mn;
        }
        __syncthreads();
        {
            int r = t >> 1, sg = t & 1;
            float mn = Mrow[r];
            float s = 0.f;
            #pragma unroll
            for (int x = 0; x < 32; ++x) {
                float p = __expf(Ss[r][sg * 32 + x] - mn);
                Ps[r * 72 + sg * 32 + x] = (bf16_t)p;
                s += p;
            }
            Lpart[r][sg] = s;
        }
        __syncthreads();
        if (t < 128)
            Lrow[t] = Lrow[t] * Arow[t] + Lpart[t][0] + Lpart[t][1];

        // ---- MFMA PV: rescale O by alpha(q), then ctx^T += V^T P^T ----
        #pragma unroll
        for (int qt = 0; qt < 2; ++qt) {
            const float al = Arow[w * 32 + qt * 16 + lane15];
            #pragma unroll
            for (int ht = 0; ht < 8; ++ht)
                #pragma unroll
                for (int c = 0; c < 4; ++c) O[ht][qt][c] *= al;
        }
        #pragma unroll
        for (int ks = 0; ks < 2; ++ks) {
            const int rcp = (ks * 4 + quad) * 8;          // Ps: NOT swizzled
            const int rcv = rcp ^ swr;                    // Vts: swizzled
            bf16x8 av[8], bp[2];
            #pragma unroll
            for (int ht = 0; ht < 8; ++ht)
                av[ht] = *(const bf16x8*)&Vts[(ht * 16 + lane15) * 64 + rcv];
            #pragma unroll
            for (int qt = 0; qt < 2; ++qt)
                bp[qt] = *(const bf16x8*)&Ps[(w * 32 + qt * 16 + lane15) * 72 + rcp];
            #pragma unroll
            for (int ht = 0; ht < 8; ++ht)
                #pragma unroll
                for (int qt = 0; qt < 2; ++qt)
                    O[ht][qt] = MFMA16(av[ht], bp[qt], O[ht][qt]);
        }
    }

    __syncthreads();   // final Lrow visible

    #pragma unroll
    for (int qt = 0; qt < 2; ++qt) {
        const float linv = 1.0f / Lrow[w * 32 + qt * 16 + lane15];
        const int s = q0 + w * 32 + qt * 16 + lane15;
        #pragma unroll
        for (int ht = 0; ht < 8; ++ht) {
            bf16x4 o;
            #pragma unroll
            for (int c = 0; c < 4; ++c) o[c] = (bf16_t)(O[ht][qt][c] * linv);
            *(bf16x4*)&CTX[((size_t)(b * Sc + s)) * HHDc + h * HDc + ht * 16 + quad * 4] = o;
        }
    }
}

// ---------------------------------------------------------------------------
// ws slots (total 134,217,728 B — proven footprint):
//   S0 Qf  fp32 8M @ 0          -> Kh  (bf16, after Qf dead)
//   S1 Kf  fp32 8M @ 33554432   -> Vth (bf16 16MB, after Kf dead)
//   S2 Vf  fp32 8M @ 67108864   -> CTX (bf16, after prep_vt)
//   S3 xb  bf16 8M @ 100663296  -> Qh  (after xb dead)
//   S4 WT  bf16 4M @ 117440512  (shared Wq/Wk/Wv slot)
//   S5 WoT bf16 4M @ 125829120
// ---------------------------------------------------------------------------
extern "C" void kernel_launch(void* const* d_in, const int* in_sizes, int n_in,
                              void* d_out, int out_size, void* d_ws, size_t ws_size,
                              hipStream_t stream)
{
    const float* x  = (const float*)d_in[0];
    const float* Wq = (const float*)d_in[2];
    const float* Wk = (const float*)d_in[3];
    const float* Wv = (const float*)d_in[4];
    const float* Wo = (const float*)d_in[5];
    float* out = (float*)d_out;

    float*  Qf  = (float*)d_ws;
    float*  Kf  = Qf + 8388608;
    float*  Vf  = Kf + 8388608;
    bf16_t* xb  = (bf16_t*)(Vf + 8388608);
    bf16_t* WT  = xb + 8388608;
    bf16_t* WoT = WT + 4194304;
    bf16_t* Qh  = xb;             // alias: xb dead after V gemm
    bf16_t* Kh  = (bf16_t*)Qf;    // alias: Qf dead after Q cast
    bf16_t* Vth = (bf16_t*)Kf;    // alias: Kf dead after K cast
    bf16_t* CTX = (bf16_t*)Vf;    // alias: Vf dead after prep_vt

    dim3 tw(32, 32);
    dim3 gg(16, 32);

    convert_x<<<8192, 256, 0, stream>>>(x, xb);
    transpose_w<<<tw, 256, 0, stream>>>(Wo, WoT);

    transpose_w<<<tw, 256, 0, stream>>>(Wq, WT);
    gemm_bt<<<gg, 256, 0, stream>>>(xb, WT, Qf);
    transpose_w<<<tw, 256, 0, stream>>>(Wk, WT);
    gemm_bt<<<gg, 256, 0, stream>>>(xb, WT, Kf);
    transpose_w<<<tw, 256, 0, stream>>>(Wv, WT);
    gemm_bt<<<gg, 256, 0, stream>>>(xb, WT, Vf);

    rope_k<<<(BSc * Hc * 64) / 256, 256, 0, stream>>>(Qf, Kf);

    scale_cast<<<8192, 256, 0, stream>>>(Qf, Qh, 0.08838834764831845f);
    scale_cast<<<8192, 256, 0, stream>>>(Kf, Kh, 1.0f);
    prep_vt<<<dim3(32, 2, 32), 256, 0, stream>>>(Vf, Vth);

    attn_v3<<<dim3(16, 32), 256, 0, stream>>>(Qh, Kh, Vth, CTX);

    gemm_bt<<<gg, 256, 0, stream>>>(CTX, WoT, out);
}

// Round 2
// 540.798 us; speedup vs baseline: 1.1865x; 1.0767x over previous
//
#include <hip/hip_runtime.h>
#include <math.h>

// (B,S,D,H,HD) = (2,2048,2048,16,128)
#define Bc   2
#define Sc   2048
#define Dc   2048
#define Hc   16
#define HDc  128
#define BSc  4096
#define HHDc 2048

typedef __bf16 bf16_t;
typedef __bf16 bf16x8 __attribute__((ext_vector_type(8)));
typedef __bf16 bf16x4 __attribute__((ext_vector_type(4)));
typedef float  f32x4  __attribute__((ext_vector_type(4)));

#define AS1(p) ((const __attribute__((address_space(1))) void*)(p))
#define AS3(p) ((__attribute__((address_space(3))) void*)(p))

#define MFMA16(a,b,c) __builtin_amdgcn_mfma_f32_16x16x32_bf16((a),(b),(c),0,0,0)

// ---------------------------------------------------------------------------
// x: fp32 -> bf16 (same layout)  [verified]
// ---------------------------------------------------------------------------
__global__ void convert_x(const float* __restrict__ x, bf16_t* __restrict__ xb)
{
    const size_t i = ((size_t)blockIdx.x * 256 + threadIdx.x) * 4;
    float4 v = *(const float4*)&x[i];
    bf16x4 o; o[0]=(bf16_t)v.x; o[1]=(bf16_t)v.y; o[2]=(bf16_t)v.z; o[3]=(bf16_t)v.w;
    *(bf16x4*)&xb[i] = o;
}

// ---------------------------------------------------------------------------
// fp32 -> bf16 with scale, same layout  [R5-verified]
// ---------------------------------------------------------------------------
__global__ void scale_cast(const float* __restrict__ in, bf16_t* __restrict__ out,
                           float s)
{
    const size_t i = ((size_t)blockIdx.x * 256 + threadIdx.x) * 4;
    float4 v = *(const float4*)&in[i];
    bf16x4 o; o[0]=(bf16_t)(v.x*s); o[1]=(bf16_t)(v.y*s);
    o[2]=(bf16_t)(v.z*s); o[3]=(bf16_t)(v.w*s);
    *(bf16x4*)&out[i] = o;
}

// ---------------------------------------------------------------------------
// W [K=2048][N=2048] fp32 -> W^T [N][K] bf16  [verified]
// ---------------------------------------------------------------------------
__global__ __launch_bounds__(256) void transpose_w(const float* __restrict__ in,
                                                   bf16_t* __restrict__ out)
{
    __shared__ float T[64][65];
    const int t = threadIdx.x;
    const int r0 = blockIdx.y * 64, c0 = blockIdx.x * 64;
    #pragma unroll
    for (int i = 0; i < 4; ++i) {
        int row = i * 16 + (t >> 4);
        int c4  = (t & 15) * 4;
        float4 v = *(const float4*)&in[(size_t)(r0 + row) * 2048 + c0 + c4];
        T[row][c4] = v.x; T[row][c4+1] = v.y; T[row][c4+2] = v.z; T[row][c4+3] = v.w;
    }
    __syncthreads();
    #pragma unroll
    for (int i = 0; i < 4; ++i) {
        int orow = i * 16 + (t >> 4);
        int c4   = (t & 15) * 4;
        bf16x4 o;
        #pragma unroll
        for (int j = 0; j < 4; ++j) o[j] = (bf16_t)T[c4 + j][orow];
        *(bf16x4*)&out[(size_t)(c0 + orow) * 2048 + r0 + c4] = o;
    }
}

// ---------------------------------------------------------------------------
// fp32 V [b*S+s][h*128+hd] -> bf16 V^T [bh][hd][s]  (transpose_w pattern)
// ---------------------------------------------------------------------------
__global__ __launch_bounds__(256) void prep_vt(const float* __restrict__ V,
                                               bf16_t* __restrict__ Vt)
{
    __shared__ float T[64][65];
    const int t = threadIdx.x;
    const int s0 = blockIdx.x * 64;
    const int c0 = blockIdx.y * 64;          // hd tile (0 or 64)
    const int bh = blockIdx.z;
    const int b = bh >> 4, h = bh & 15;
    #pragma unroll
    for (int i = 0; i < 4; ++i) {
        int row = i * 16 + (t >> 4);         // s-local
        int c4  = (t & 15) * 4;              // hd-local
        float4 v = *(const float4*)&V[((size_t)(b * Sc + s0 + row)) * HHDc + h * HDc + c0 + c4];
        T[row][c4] = v.x; T[row][c4+1] = v.y; T[row][c4+2] = v.z; T[row][c4+3] = v.w;
    }
    __syncthreads();
    #pragma unroll
    for (int i = 0; i < 4; ++i) {
        int orow = i * 16 + (t >> 4);        // hd-local
        int c4   = (t & 15) * 4;             // s-local
        bf16x4 o;
        #pragma unroll
        for (int j = 0; j < 4; ++j) o[j] = (bf16_t)T[c4 + j][orow];
        *(bf16x4*)&Vt[((size_t)bh * HDc + c0 + orow) * Sc + s0 + c4] = o;
    }
}

// ---------------------------------------------------------------------------
// GEMM: C[4096][2048] = A * Bt^T, bf16 in fp32 out  [verified]
// ---------------------------------------------------------------------------
__global__ __launch_bounds__(256) void gemm_bt(const bf16_t* __restrict__ A,
                                               const bf16_t* __restrict__ Bt,
                                               float* __restrict__ C)
{
    __shared__ bf16_t As[128 * 64];
    __shared__ bf16_t Bs[128 * 64];
    const int t = threadIdx.x;
    const int w = t >> 6, l = t & 63;
    const int wm = w >> 1, wn = w & 1;
    const int lane15 = l & 15, quad = l >> 4;
    const int m0 = blockIdx.y * 128, n0 = blockIdx.x * 128;

    f32x4 acc[4][4];
    #pragma unroll
    for (int i = 0; i < 4; ++i)
        #pragma unroll
        for (int j = 0; j < 4; ++j)
            #pragma unroll
            for (int c = 0; c < 4; ++c) acc[i][j][c] = 0.f;

    const int srow = w * 8 + (l >> 3);
    const int sch  = l & 7;

    for (int k0 = 0; k0 < 2048; k0 += 64) {
        __syncthreads();
        #pragma unroll
        for (int p = 0; p < 4; ++p) {
            __builtin_amdgcn_global_load_lds(
                AS1(A + (size_t)(m0 + p * 32 + srow) * 2048 + k0 + sch * 8),
                AS3(&As[(p * 32 + w * 8) * 64]), 16, 0, 0);
            __builtin_amdgcn_global_load_lds(
                AS1(Bt + (size_t)(n0 + p * 32 + srow) * 2048 + k0 + sch * 8),
                AS3(&Bs[(p * 32 + w * 8) * 64]), 16, 0, 0);
        }
        __syncthreads();
        #pragma unroll
        for (int ks = 0; ks < 2; ++ks) {
            const int rc = (ks * 4 + quad) * 8;
            bf16x8 a[4], b[4];
            #pragma unroll
            for (int mt = 0; mt < 4; ++mt)
                a[mt] = *(const bf16x8*)&As[(wm * 64 + mt * 16 + lane15) * 64 + rc];
            #pragma unroll
            for (int nt = 0; nt < 4; ++nt)
                b[nt] = *(const bf16x8*)&Bs[(wn * 64 + nt * 16 + lane15) * 64 + rc];
            #pragma unroll
            for (int mt = 0; mt < 4; ++mt)
                #pragma unroll
                for (int nt = 0; nt < 4; ++nt)
                    acc[mt][nt] = MFMA16(a[mt], b[nt], acc[mt][nt]);
        }
    }

    #pragma unroll
    for (int mt = 0; mt < 4; ++mt)
        #pragma unroll
        for (int nt = 0; nt < 4; ++nt)
            #pragma unroll
            for (int r = 0; r < 4; ++r) {
                const int gm = m0 + wm * 64 + mt * 16 + quad * 4 + r;
                const int gn = n0 + wn * 64 + nt * 16 + lane15;
                C[(size_t)gm * 2048 + gn] = acc[mt][nt][r];
            }
}

// ---------------------------------------------------------------------------
// RoPE in-place on fp32 Q,K  [verified]
// ---------------------------------------------------------------------------
__global__ void rope_k(float* __restrict__ Q, float* __restrict__ K)
{
    const int idx  = blockIdx.x * blockDim.x + threadIdx.x;
    const int j    = idx & 63;
    const int h    = (idx >> 6) & (Hc - 1);
    const int sabs = idx >> 10;
    const int s    = sabs & (Sc - 1);

    const float freq = expf(-(float)j * 0.14391156514261520f);
    const float ang  = (float)s * freq;
    float sn, cs;
    sincosf(ang, &sn, &cs);

    const size_t base = (size_t)sabs * HHDc + (size_t)h * HDc + j;
    float q1 = Q[base], q2 = Q[base + 64];
    Q[base]      = q1 * cs - q2 * sn;
    Q[base + 64] = q2 * cs + q1 * sn;
    float k1 = K[base], k2 = K[base + 64];
    K[base]      = k1 * cs - k2 * sn;
    K[base + 64] = k2 * cs + k1 * sn;
}

// ---------------------------------------------------------------------------
// attn_v4: v3 + (1) Q tile in registers (no Qs), (2) fully in-register
// online softmax via quad-group __shfl_xor (no Ss / Mpart / Lpart / serial
// phases), (3) Ps/Arow/Lrow are wave-private -> only 2 barriers per k-tile.
// LDS: Ks 16K + Vts 16K + Ps 18K + Arow/Lrow 1K = 52 KB -> >=2 blocks/CU.
// QK^T C-layout (R5-verified): score row q = w*32+mt*16+quad*4+r lives in
// sc[mt][nt][r] across the 16 lanes sharing `quad` (col = nt*16+lane15).
// Row reduce = 3 in-reg ops + shfl_xor(1,2,4,8) within the 16-lane group.
// ---------------------------------------------------------------------------
__global__ __launch_bounds__(256, 2) void attn_v4(const bf16_t* __restrict__ Q,
                                                  const bf16_t* __restrict__ K,
                                                  const bf16_t* __restrict__ Vt,
                                                  bf16_t* __restrict__ CTX)
{
    __shared__ bf16_t Ks[64 * 128];    // [k_local][hd]   (col-swizzled)
    __shared__ bf16_t Vts[128 * 64];   // [hd][key_local] (col-swizzled)
    __shared__ bf16_t Ps[128 * 72];    // bf16 P[q][key], wave-private rows
    __shared__ float  Arow[128];       // per-tile alpha, wave-private rows
    __shared__ float  Lrow[128];       // final denom, wave-private rows

    const int t = threadIdx.x, w = t >> 6, l = t & 63;
    const int lane15 = l & 15, quad = l >> 4;
    const int swr = (lane15 & 7) * 8;          // read-side column swizzle
    const int q0 = blockIdx.x * 128;
    const int b = blockIdx.y >> 4, h = blockIdx.y & 15;
    const size_t qbase = ((size_t)(b * Sc + q0)) * HHDc + h * HDc;
    const size_t vtb   = (size_t)blockIdx.y * HDc * Sc;

    // ---- Q fragments straight to registers (one-time, 8 x dwordx4) ----
    bf16x8 qf[2][4];
    #pragma unroll
    for (int mt = 0; mt < 2; ++mt)
        #pragma unroll
        for (int ks = 0; ks < 4; ++ks)
            qf[mt][ks] = *(const bf16x8*)&Q[qbase
                + (size_t)(w * 32 + mt * 16 + lane15) * HHDc + (ks * 4 + quad) * 8];

    // online-softmax state per owned q-row (mt, r), replicated across 16 lanes
    float m_[2][4], l_[2][4];
    #pragma unroll
    for (int mt = 0; mt < 2; ++mt)
        #pragma unroll
        for (int r = 0; r < 4; ++r) { m_[mt][r] = -INFINITY; l_[mt][r] = 0.f; }

    f32x4 O[8][2];      // PV acc: O[ht][qt], hd=ht*16+quad*4+c, q=qt*16+lane15
    #pragma unroll
    for (int i = 0; i < 8; ++i)
        #pragma unroll
        for (int j = 0; j < 2; ++j)
            #pragma unroll
            for (int c = 0; c < 4; ++c) O[i][j][c] = 0.f;

    for (int kt = 0; kt < Sc / 64; ++kt) {
        __syncthreads();   // protect Ks/Vts restage vs prev iteration reads
        const size_t kbase = ((size_t)(b * Sc + kt * 64)) * HHDc + h * HDc;
        {   // stage K (bf16): rows=keys, hd contiguous; source col swizzled
            const int srow = w * 4 + (l >> 4);
            const int swk  = (srow & 7) * 8;
            const int gcol = (lane15 * 8) ^ swk;
            #pragma unroll
            for (int p = 0; p < 4; ++p)
                __builtin_amdgcn_global_load_lds(
                    AS1(K + kbase + (size_t)(p * 16 + srow) * HHDc + gcol),
                    AS3(&Ks[(p * 16 + w * 4) * 128]), 16, 0, 0);
        }
        {   // stage Vt (bf16): rows=hd, keys contiguous; source col swizzled
            const int vrow = w * 8 + (l >> 3);
            const int swv  = (vrow & 7) * 8;
            const int gcol = ((l & 7) * 8) ^ swv;
            #pragma unroll
            for (int p = 0; p < 4; ++p)
                __builtin_amdgcn_global_load_lds(
                    AS1(Vt + vtb + (size_t)(p * 32 + vrow) * Sc + kt * 64 + gcol),
                    AS3(&Vts[(p * 32 + w * 8) * 64]), 16, 0, 0);
        }
        __syncthreads();

        // ---- MFMA QK^T: wave w owns q-rows w*32..w*32+31, all 64 keys ----
        f32x4 sc[2][4];
        #pragma unroll
        for (int i = 0; i < 2; ++i)
            #pragma unroll
            for (int j = 0; j < 4; ++j)
                #pragma unroll
                for (int c = 0; c < 4; ++c) sc[i][j][c] = 0.f;
        #pragma unroll
        for (int ks = 0; ks < 4; ++ks) {
            const int rc = ((ks * 4 + quad) * 8) ^ swr;   // swizzled column
            bf16x8 bk[4];
            #pragma unroll
            for (int nt = 0; nt < 4; ++nt)
                bk[nt] = *(const bf16x8*)&Ks[(nt * 16 + lane15) * 128 + rc];
            #pragma unroll
            for (int mt = 0; mt < 2; ++mt)
                #pragma unroll
                for (int nt = 0; nt < 4; ++nt)
                    sc[mt][nt] = MFMA16(qf[mt][ks], bk[nt], sc[mt][nt]);
        }

        // ---- in-register online softmax (per owned q-row) ----
        #pragma unroll
        for (int mt = 0; mt < 2; ++mt)
            #pragma unroll
            for (int r = 0; r < 4; ++r) {
                const float v0 = sc[mt][0][r], v1 = sc[mt][1][r];
                const float v2 = sc[mt][2][r], v3 = sc[mt][3][r];
                float tm = fmaxf(fmaxf(v0, v1), fmaxf(v2, v3));
                tm = fmaxf(tm, __shfl_xor(tm, 1));
                tm = fmaxf(tm, __shfl_xor(tm, 2));
                tm = fmaxf(tm, __shfl_xor(tm, 4));
                tm = fmaxf(tm, __shfl_xor(tm, 8));
                const float mo = m_[mt][r];
                const float mn = fmaxf(mo, tm);
                const float al = __expf(mo - mn);
                m_[mt][r] = mn;
                const float p0 = __expf(v0 - mn), p1 = __expf(v1 - mn);
                const float p2 = __expf(v2 - mn), p3 = __expf(v3 - mn);
                float ts = (p0 + p1) + (p2 + p3);
                ts += __shfl_xor(ts, 1);
                ts += __shfl_xor(ts, 2);
                ts += __shfl_xor(ts, 4);
                ts += __shfl_xor(ts, 8);
                l_[mt][r] = l_[mt][r] * al + ts;
                const int qrow = w * 32 + mt * 16 + quad * 4 + r;
                Ps[qrow * 72 +  0 + lane15] = (bf16_t)p0;
                Ps[qrow * 72 + 16 + lane15] = (bf16_t)p1;
                Ps[qrow * 72 + 32 + lane15] = (bf16_t)p2;
                Ps[qrow * 72 + 48 + lane15] = (bf16_t)p3;
                if (lane15 == mt * 4 + r) Arow[qrow] = al;
            }
        // Ps/Arow are wave-private: wave-synchronous exec + lgkmcnt ordering
        // make a block barrier unnecessary before the PV reads below.

        // ---- MFMA PV: rescale O by alpha(q), then ctx^T += V^T P^T ----
        #pragma unroll
        for (int qt = 0; qt < 2; ++qt) {
            const float al = Arow[w * 32 + qt * 16 + lane15];
            #pragma unroll
            for (int ht = 0; ht < 8; ++ht)
                #pragma unroll
                for (int c = 0; c < 4; ++c) O[ht][qt][c] *= al;
        }
        #pragma unroll
        for (int ks = 0; ks < 2; ++ks) {
            const int rcp = (ks * 4 + quad) * 8;          // Ps: NOT swizzled
            const int rcv = rcp ^ swr;                    // Vts: swizzled
            bf16x8 av[8], bp[2];
            #pragma unroll
            for (int ht = 0; ht < 8; ++ht)
                av[ht] = *(const bf16x8*)&Vts[(ht * 16 + lane15) * 64 + rcv];
            #pragma unroll
            for (int qt = 0; qt < 2; ++qt)
                bp[qt] = *(const bf16x8*)&Ps[(w * 32 + qt * 16 + lane15) * 72 + rcp];
            #pragma unroll
            for (int ht = 0; ht < 8; ++ht)
                #pragma unroll
                for (int qt = 0; qt < 2; ++qt)
                    O[ht][qt] = MFMA16(av[ht], bp[qt], O[ht][qt]);
        }
    }

    // publish per-row denom (wave-private) and write out
    #pragma unroll
    for (int mt = 0; mt < 2; ++mt)
        #pragma unroll
        for (int r = 0; r < 4; ++r)
            if (lane15 == mt * 4 + r)
                Lrow[w * 32 + mt * 16 + quad * 4 + r] = l_[mt][r];
    __syncthreads();

    #pragma unroll
    for (int qt = 0; qt < 2; ++qt) {
        const float linv = 1.0f / Lrow[w * 32 + qt * 16 + lane15];
        const int s = q0 + w * 32 + qt * 16 + lane15;
        #pragma unroll
        for (int ht = 0; ht < 8; ++ht) {
            bf16x4 o;
            #pragma unroll
            for (int c = 0; c < 4; ++c) o[c] = (bf16_t)(O[ht][qt][c] * linv);
            *(bf16x4*)&CTX[((size_t)(b * Sc + s)) * HHDc + h * HDc + ht * 16 + quad * 4] = o;
        }
    }
}

// ---------------------------------------------------------------------------
// ws slots (total 134,217,728 B — proven footprint):
//   S0 Qf  fp32 8M @ 0          -> Kh  (bf16, after Qf dead)
//   S1 Kf  fp32 8M @ 33554432   -> Vth (bf16 16MB, after Kf dead)
//   S2 Vf  fp32 8M @ 67108864   -> CTX (bf16, after prep_vt)
//   S3 xb  bf16 8M @ 100663296  -> Qh  (after xb dead)
//   S4 WT  bf16 4M @ 117440512  (shared Wq/Wk/Wv slot)
//   S5 WoT bf16 4M @ 125829120
// ---------------------------------------------------------------------------
extern "C" void kernel_launch(void* const* d_in, const int* in_sizes, int n_in,
                              void* d_out, int out_size, void* d_ws, size_t ws_size,
                              hipStream_t stream)
{
    const float* x  = (const float*)d_in[0];
    const float* Wq = (const float*)d_in[2];
    const float* Wk = (const float*)d_in[3];
    const float* Wv = (const float*)d_in[4];
    const float* Wo = (const float*)d_in[5];
    float* out = (float*)d_out;

    float*  Qf  = (float*)d_ws;
    float*  Kf  = Qf + 8388608;
    float*  Vf  = Kf + 8388608;
    bf16_t* xb  = (bf16_t*)(Vf + 8388608);
    bf16_t* WT  = xb + 8388608;
    bf16_t* WoT = WT + 4194304;
    bf16_t* Qh  = xb;             // alias: xb dead after V gemm
    bf16_t* Kh  = (bf16_t*)Qf;    // alias: Qf dead after Q cast
    bf16_t* Vth = (bf16_t*)Kf;    // alias: Kf dead after K cast
    bf16_t* CTX = (bf16_t*)Vf;    // alias: Vf dead after prep_vt

    dim3 tw(32, 32);
    dim3 gg(16, 32);

    convert_x<<<8192, 256, 0, stream>>>(x, xb);
    transpose_w<<<tw, 256, 0, stream>>>(Wo, WoT);

    transpose_w<<<tw, 256, 0, stream>>>(Wq, WT);
    gemm_bt<<<gg, 256, 0, stream>>>(xb, WT, Qf);
    transpose_w<<<tw, 256, 0, stream>>>(Wk, WT);
    gemm_bt<<<gg, 256, 0, stream>>>(xb, WT, Kf);
    transpose_w<<<tw, 256, 0, stream>>>(Wv, WT);
    gemm_bt<<<gg, 256, 0, stream>>>(xb, WT, Vf);

    rope_k<<<(BSc * Hc * 64) / 256, 256, 0, stream>>>(Qf, Kf);

    scale_cast<<<8192, 256, 0, stream>>>(Qf, Qh, 0.08838834764831845f);
    scale_cast<<<8192, 256, 0, stream>>>(Kf, Kh, 1.0f);
    prep_vt<<<dim3(32, 2, 32), 256, 0, stream>>>(Vf, Vth);

    attn_v4<<<dim3(16, 32), 256, 0, stream>>>(Qh, Kh, Vth, CTX);

    gemm_bt<<<gg, 256, 0, stream>>>(CTX, WoT, out);
}

// Round 3
// 512.187 us; speedup vs baseline: 1.2527x; 1.0559x over previous
//
#include <hip/hip_runtime.h>
#include <math.h>

// (B,S,D,H,HD) = (2,2048,2048,16,128)
#define Bc   2
#define Sc   2048
#define Dc   2048
#define Hc   16
#define HDc  128
#define BSc  4096
#define HHDc 2048

typedef __bf16 bf16_t;
typedef __bf16 bf16x8 __attribute__((ext_vector_type(8)));
typedef __bf16 bf16x4 __attribute__((ext_vector_type(4)));
typedef float  f32x4  __attribute__((ext_vector_type(4)));

#define AS1(p) ((const __attribute__((address_space(1))) void*)(p))
#define AS3(p) ((__attribute__((address_space(3))) void*)(p))

#define MFMA16(a,b,c) __builtin_amdgcn_mfma_f32_16x16x32_bf16((a),(b),(c),0,0,0)

// ---------------------------------------------------------------------------
// x: fp32 -> bf16 (same layout)  [verified]
// ---------------------------------------------------------------------------
__global__ void convert_x(const float* __restrict__ x, bf16_t* __restrict__ xb)
{
    const size_t i = ((size_t)blockIdx.x * 256 + threadIdx.x) * 4;
    float4 v = *(const float4*)&x[i];
    bf16x4 o; o[0]=(bf16_t)v.x; o[1]=(bf16_t)v.y; o[2]=(bf16_t)v.z; o[3]=(bf16_t)v.w;
    *(bf16x4*)&xb[i] = o;
}

// ---------------------------------------------------------------------------
// W [K=2048][N=2048] fp32 -> W^T [N][K] bf16  [verified]
// ---------------------------------------------------------------------------
__global__ __launch_bounds__(256) void transpose_w(const float* __restrict__ in,
                                                   bf16_t* __restrict__ out)
{
    __shared__ float T[64][65];
    const int t = threadIdx.x;
    const int r0 = blockIdx.y * 64, c0 = blockIdx.x * 64;
    #pragma unroll
    for (int i = 0; i < 4; ++i) {
        int row = i * 16 + (t >> 4);
        int c4  = (t & 15) * 4;
        float4 v = *(const float4*)&in[(size_t)(r0 + row) * 2048 + c0 + c4];
        T[row][c4] = v.x; T[row][c4+1] = v.y; T[row][c4+2] = v.z; T[row][c4+3] = v.w;
    }
    __syncthreads();
    #pragma unroll
    for (int i = 0; i < 4; ++i) {
        int orow = i * 16 + (t >> 4);
        int c4   = (t & 15) * 4;
        bf16x4 o;
        #pragma unroll
        for (int j = 0; j < 4; ++j) o[j] = (bf16_t)T[c4 + j][orow];
        *(bf16x4*)&out[(size_t)(c0 + orow) * 2048 + r0 + c4] = o;
    }
}

// ---------------------------------------------------------------------------
// bf16 V [b*S+s][h*128+hd] -> bf16 V^T [bh][hd][s]  (transpose_w pattern)
// ---------------------------------------------------------------------------
__global__ __launch_bounds__(256) void prep_vtb(const bf16_t* __restrict__ V,
                                                bf16_t* __restrict__ Vt)
{
    __shared__ float T[64][65];
    const int t = threadIdx.x;
    const int s0 = blockIdx.x * 64;
    const int c0 = blockIdx.y * 64;          // hd tile (0 or 64)
    const int bh = blockIdx.z;
    const int b = bh >> 4, h = bh & 15;
    #pragma unroll
    for (int i = 0; i < 4; ++i) {
        int row = i * 16 + (t >> 4);         // s-local
        int c4  = (t & 15) * 4;              // hd-local
        bf16x4 v = *(const bf16x4*)&V[((size_t)(b * Sc + s0 + row)) * HHDc + h * HDc + c0 + c4];
        #pragma unroll
        for (int j = 0; j < 4; ++j) T[row][c4 + j] = (float)v[j];
    }
    __syncthreads();
    #pragma unroll
    for (int i = 0; i < 4; ++i) {
        int orow = i * 16 + (t >> 4);        // hd-local
        int c4   = (t & 15) * 4;             // s-local
        bf16x4 o;
        #pragma unroll
        for (int j = 0; j < 4; ++j) o[j] = (bf16_t)T[c4 + j][orow];
        *(bf16x4*)&Vt[((size_t)bh * HDc + c0 + orow) * Sc + s0 + c4] = o;
    }
}

// ---------------------------------------------------------------------------
// Fused QKV GEMM: C[4096][6144] = xb * WT3^T; proven gemm_bt inner loop.
// Output router: n<2048 -> Qf fp32; n<4096 -> Kf fp32; else -> Vb bf16.
// (V-as-bf16 is bit-identical to old fp32-gemm + prep_vt cast path.)
// ---------------------------------------------------------------------------
__global__ __launch_bounds__(256) void qkv_gemm(const bf16_t* __restrict__ A,
                                                const bf16_t* __restrict__ Bt,
                                                float* __restrict__ Qf,
                                                float* __restrict__ Kf,
                                                bf16_t* __restrict__ Vb)
{
    __shared__ bf16_t As[128 * 64];
    __shared__ bf16_t Bs[128 * 64];
    const int t = threadIdx.x;
    const int w = t >> 6, l = t & 63;
    const int wm = w >> 1, wn = w & 1;
    const int lane15 = l & 15, quad = l >> 4;
    const int m0 = blockIdx.y * 128, n0 = blockIdx.x * 128;

    f32x4 acc[4][4];
    #pragma unroll
    for (int i = 0; i < 4; ++i)
        #pragma unroll
        for (int j = 0; j < 4; ++j)
            #pragma unroll
            for (int c = 0; c < 4; ++c) acc[i][j][c] = 0.f;

    const int srow = w * 8 + (l >> 3);
    const int sch  = l & 7;

    for (int k0 = 0; k0 < 2048; k0 += 64) {
        __syncthreads();
        #pragma unroll
        for (int p = 0; p < 4; ++p) {
            __builtin_amdgcn_global_load_lds(
                AS1(A + (size_t)(m0 + p * 32 + srow) * 2048 + k0 + sch * 8),
                AS3(&As[(p * 32 + w * 8) * 64]), 16, 0, 0);
            __builtin_amdgcn_global_load_lds(
                AS1(Bt + (size_t)(n0 + p * 32 + srow) * 2048 + k0 + sch * 8),
                AS3(&Bs[(p * 32 + w * 8) * 64]), 16, 0, 0);
        }
        __syncthreads();
        #pragma unroll
        for (int ks = 0; ks < 2; ++ks) {
            const int rc = (ks * 4 + quad) * 8;
            bf16x8 a[4], b[4];
            #pragma unroll
            for (int mt = 0; mt < 4; ++mt)
                a[mt] = *(const bf16x8*)&As[(wm * 64 + mt * 16 + lane15) * 64 + rc];
            #pragma unroll
            for (int nt = 0; nt < 4; ++nt)
                b[nt] = *(const bf16x8*)&Bs[(wn * 64 + nt * 16 + lane15) * 64 + rc];
            #pragma unroll
            for (int mt = 0; mt < 4; ++mt)
                #pragma unroll
                for (int nt = 0; nt < 4; ++nt)
                    acc[mt][nt] = MFMA16(a[mt], b[nt], acc[mt][nt]);
        }
    }

    if (n0 < 4096) {
        float* __restrict__ dst = (n0 < 2048) ? Qf : Kf;
        const int nb = n0 & 2047;
        #pragma unroll
        for (int mt = 0; mt < 4; ++mt)
            #pragma unroll
            for (int nt = 0; nt < 4; ++nt)
                #pragma unroll
                for (int r = 0; r < 4; ++r) {
                    const int gm = m0 + wm * 64 + mt * 16 + quad * 4 + r;
                    const int gn = nb + wn * 64 + nt * 16 + lane15;
                    dst[(size_t)gm * 2048 + gn] = acc[mt][nt][r];
                }
    } else {
        const int nb = n0 - 4096;
        #pragma unroll
        for (int mt = 0; mt < 4; ++mt)
            #pragma unroll
            for (int nt = 0; nt < 4; ++nt)
                #pragma unroll
                for (int r = 0; r < 4; ++r) {
                    const int gm = m0 + wm * 64 + mt * 16 + quad * 4 + r;
                    const int gn = nb + wn * 64 + nt * 16 + lane15;
                    Vb[(size_t)gm * 2048 + gn] = (bf16_t)acc[mt][nt][r];
                }
    }
}

// ---------------------------------------------------------------------------
// GEMM: C[4096][2048] = A * Bt^T, bf16 in fp32 out  [verified] (final proj)
// ---------------------------------------------------------------------------
__global__ __launch_bounds__(256) void gemm_bt(const bf16_t* __restrict__ A,
                                               const bf16_t* __restrict__ Bt,
                                               float* __restrict__ C)
{
    __shared__ bf16_t As[128 * 64];
    __shared__ bf16_t Bs[128 * 64];
    const int t = threadIdx.x;
    const int w = t >> 6, l = t & 63;
    const int wm = w >> 1, wn = w & 1;
    const int lane15 = l & 15, quad = l >> 4;
    const int m0 = blockIdx.y * 128, n0 = blockIdx.x * 128;

    f32x4 acc[4][4];
    #pragma unroll
    for (int i = 0; i < 4; ++i)
        #pragma unroll
        for (int j = 0; j < 4; ++j)
            #pragma unroll
            for (int c = 0; c < 4; ++c) acc[i][j][c] = 0.f;

    const int srow = w * 8 + (l >> 3);
    const int sch  = l & 7;

    for (int k0 = 0; k0 < 2048; k0 += 64) {
        __syncthreads();
        #pragma unroll
        for (int p = 0; p < 4; ++p) {
            __builtin_amdgcn_global_load_lds(
                AS1(A + (size_t)(m0 + p * 32 + srow) * 2048 + k0 + sch * 8),
                AS3(&As[(p * 32 + w * 8) * 64]), 16, 0, 0);
            __builtin_amdgcn_global_load_lds(
                AS1(Bt + (size_t)(n0 + p * 32 + srow) * 2048 + k0 + sch * 8),
                AS3(&Bs[(p * 32 + w * 8) * 64]), 16, 0, 0);
        }
        __syncthreads();
        #pragma unroll
        for (int ks = 0; ks < 2; ++ks) {
            const int rc = (ks * 4 + quad) * 8;
            bf16x8 a[4], b[4];
            #pragma unroll
            for (int mt = 0; mt < 4; ++mt)
                a[mt] = *(const bf16x8*)&As[(wm * 64 + mt * 16 + lane15) * 64 + rc];
            #pragma unroll
            for (int nt = 0; nt < 4; ++nt)
                b[nt] = *(const bf16x8*)&Bs[(wn * 64 + nt * 16 + lane15) * 64 + rc];
            #pragma unroll
            for (int mt = 0; mt < 4; ++mt)
                #pragma unroll
                for (int nt = 0; nt < 4; ++nt)
                    acc[mt][nt] = MFMA16(a[mt], b[nt], acc[mt][nt]);
        }
    }

    #pragma unroll
    for (int mt = 0; mt < 4; ++mt)
        #pragma unroll
        for (int nt = 0; nt < 4; ++nt)
            #pragma unroll
            for (int r = 0; r < 4; ++r) {
                const int gm = m0 + wm * 64 + mt * 16 + quad * 4 + r;
                const int gn = n0 + wn * 64 + nt * 16 + lane15;
                C[(size_t)gm * 2048 + gn] = acc[mt][nt][r];
            }
}

// ---------------------------------------------------------------------------
// Fused RoPE + scale + bf16 cast: read Qf/Kf fp32, write Qh (scaled)/Kh bf16.
// Identical arithmetic order to old rope_k + scale_cast (absmax-preserving).
// Thread handles 4 consecutive j in [0,64) for both Q and K (shares sincos).
// ---------------------------------------------------------------------------
__global__ void rope_scale_cast(const float* __restrict__ Qf,
                                const float* __restrict__ Kf,
                                bf16_t* __restrict__ Qh,
                                bf16_t* __restrict__ Kh)
{
    const int idx  = blockIdx.x * 256 + threadIdx.x;   // 1,048,576 total
    const int j4   = (idx & 15) * 4;                   // 0..60
    const int h    = (idx >> 4) & (Hc - 1);
    const int sabs = idx >> 8;
    const int s    = sabs & (Sc - 1);
    const float QS = 0.08838834764831845f;

    const size_t base = (size_t)sabs * HHDc + (size_t)h * HDc + j4;
    float4 q1 = *(const float4*)&Qf[base];
    float4 q2 = *(const float4*)&Qf[base + 64];
    float4 k1 = *(const float4*)&Kf[base];
    float4 k2 = *(const float4*)&Kf[base + 64];

    bf16x4 qo1, qo2, ko1, ko2;
    #pragma unroll
    for (int c = 0; c < 4; ++c) {
        const float freq = expf(-(float)(j4 + c) * 0.14391156514261520f);
        const float ang  = (float)s * freq;
        float sn, cs;
        sincosf(ang, &sn, &cs);
        const float a = ((const float*)&q1)[c], bq = ((const float*)&q2)[c];
        const float x = ((const float*)&k1)[c], y  = ((const float*)&k2)[c];
        qo1[c] = (bf16_t)((a * cs - bq * sn) * QS);
        qo2[c] = (bf16_t)((bq * cs + a * sn) * QS);
        ko1[c] = (bf16_t)(x * cs - y * sn);
        ko2[c] = (bf16_t)(y * cs + x * sn);
    }
    *(bf16x4*)&Qh[base]      = qo1;
    *(bf16x4*)&Qh[base + 64] = qo2;
    *(bf16x4*)&Kh[base]      = ko1;
    *(bf16x4*)&Kh[base + 64] = ko2;
}

// ---------------------------------------------------------------------------
// attn_v5: identical algorithm/layouts to verified attn_v4, re-parameterized
// to 8 waves x 16 q-rows (512 threads) so 2 blocks/CU = 16 waves/CU (~45%
// occupancy vs 21%). Adds T5 s_setprio around both MFMA clusters.
// LDS: Ks 16K + Vts 16K + Ps 18K + 1K = 51 KB.
// ---------------------------------------------------------------------------
__global__ __launch_bounds__(512, 4) void attn_v5(const bf16_t* __restrict__ Q,
                                                  const bf16_t* __restrict__ K,
                                                  const bf16_t* __restrict__ Vt,
                                                  bf16_t* __restrict__ CTX)
{
    __shared__ bf16_t Ks[64 * 128];    // [k_local][hd]   (col-swizzled)
    __shared__ bf16_t Vts[128 * 64];   // [hd][key_local] (col-swizzled)
    __shared__ bf16_t Ps[128 * 72];    // bf16 P[q][key], wave-private rows
    __shared__ float  Arow[128];       // per-tile alpha, wave-private rows
    __shared__ float  Lrow[128];       // final denom, wave-private rows

    const int t = threadIdx.x, w = t >> 6, l = t & 63;
    const int lane15 = l & 15, quad = l >> 4;
    const int swr = (lane15 & 7) * 8;          // read-side column swizzle
    const int q0 = blockIdx.x * 128;
    const int b = blockIdx.y >> 4, h = blockIdx.y & 15;
    const size_t qbase = ((size_t)(b * Sc + q0)) * HHDc + h * HDc;
    const size_t vtb   = (size_t)blockIdx.y * HDc * Sc;

    // ---- Q fragments straight to registers (wave owns 16 q-rows) ----
    bf16x8 qf[4];
    #pragma unroll
    for (int ks = 0; ks < 4; ++ks)
        qf[ks] = *(const bf16x8*)&Q[qbase
            + (size_t)(w * 16 + lane15) * HHDc + (ks * 4 + quad) * 8];

    // online-softmax state per owned q-row r (qrow = w*16+quad*4+r)
    float m_[4], l_[4];
    #pragma unroll
    for (int r = 0; r < 4; ++r) { m_[r] = -INFINITY; l_[r] = 0.f; }

    f32x4 O[8];        // PV acc: O[ht], hd=ht*16+quad*4+c, q=w*16+lane15
    #pragma unroll
    for (int i = 0; i < 8; ++i)
        #pragma unroll
        for (int c = 0; c < 4; ++c) O[i][c] = 0.f;

    for (int kt = 0; kt < Sc / 64; ++kt) {
        __syncthreads();   // protect Ks/Vts restage vs prev iteration reads
        const size_t kbase = ((size_t)(b * Sc + kt * 64)) * HHDc + h * HDc;
        {   // stage K (bf16): 64 rows x 128; 512 threads x 16B = 32 rows/round
            const int srow0 = w * 4 + (l >> 4);
            #pragma unroll
            for (int p = 0; p < 2; ++p) {
                const int row = p * 32 + srow0;
                const int gcol = (lane15 * 8) ^ ((row & 7) * 8);
                __builtin_amdgcn_global_load_lds(
                    AS1(K + kbase + (size_t)row * HHDc + gcol),
                    AS3(&Ks[(p * 32 + w * 4) * 128]), 16, 0, 0);
            }
        }
        {   // stage Vt (bf16): 128 rows x 64; 64 rows/round
            const int vrow0 = w * 8 + (l >> 3);
            #pragma unroll
            for (int p = 0; p < 2; ++p) {
                const int row = p * 64 + vrow0;
                const int gcol = ((l & 7) * 8) ^ ((row & 7) * 8);
                __builtin_amdgcn_global_load_lds(
                    AS1(Vt + vtb + (size_t)row * Sc + kt * 64 + gcol),
                    AS3(&Vts[(p * 64 + w * 8) * 64]), 16, 0, 0);
            }
        }
        __syncthreads();

        // ---- MFMA QK^T: wave w owns q-rows w*16..w*16+15, all 64 keys ----
        f32x4 sc[4];
        #pragma unroll
        for (int j = 0; j < 4; ++j)
            #pragma unroll
            for (int c = 0; c < 4; ++c) sc[j][c] = 0.f;
        __builtin_amdgcn_s_setprio(1);
        #pragma unroll
        for (int ks = 0; ks < 4; ++ks) {
            const int rc = ((ks * 4 + quad) * 8) ^ swr;   // swizzled column
            bf16x8 bk[4];
            #pragma unroll
            for (int nt = 0; nt < 4; ++nt)
                bk[nt] = *(const bf16x8*)&Ks[(nt * 16 + lane15) * 128 + rc];
            #pragma unroll
            for (int nt = 0; nt < 4; ++nt)
                sc[nt] = MFMA16(qf[ks], bk[nt], sc[nt]);
        }
        __builtin_amdgcn_s_setprio(0);

        // ---- in-register online softmax (4 owned q-rows per thread) ----
        #pragma unroll
        for (int r = 0; r < 4; ++r) {
            const float v0 = sc[0][r], v1 = sc[1][r];
            const float v2 = sc[2][r], v3 = sc[3][r];
            float tm = fmaxf(fmaxf(v0, v1), fmaxf(v2, v3));
            tm = fmaxf(tm, __shfl_xor(tm, 1));
            tm = fmaxf(tm, __shfl_xor(tm, 2));
            tm = fmaxf(tm, __shfl_xor(tm, 4));
            tm = fmaxf(tm, __shfl_xor(tm, 8));
            const float mo = m_[r];
            const float mn = fmaxf(mo, tm);
            const float al = __expf(mo - mn);
            m_[r] = mn;
            const float p0 = __expf(v0 - mn), p1 = __expf(v1 - mn);
            const float p2 = __expf(v2 - mn), p3 = __expf(v3 - mn);
            float ts = (p0 + p1) + (p2 + p3);
            ts += __shfl_xor(ts, 1);
            ts += __shfl_xor(ts, 2);
            ts += __shfl_xor(ts, 4);
            ts += __shfl_xor(ts, 8);
            l_[r] = l_[r] * al + ts;
            const int qrow = w * 16 + quad * 4 + r;
            Ps[qrow * 72 +  0 + lane15] = (bf16_t)p0;
            Ps[qrow * 72 + 16 + lane15] = (bf16_t)p1;
            Ps[qrow * 72 + 32 + lane15] = (bf16_t)p2;
            Ps[qrow * 72 + 48 + lane15] = (bf16_t)p3;
            if (lane15 == r) Arow[qrow] = al;
        }
        // Ps/Arow are wave-private: wave-synchronous exec + lgkmcnt ordering
        // make a block barrier unnecessary before the PV reads below.

        // ---- MFMA PV: rescale O by alpha(q), then ctx^T += V^T P^T ----
        {
            const float al = Arow[w * 16 + lane15];
            #pragma unroll
            for (int ht = 0; ht < 8; ++ht)
                #pragma unroll
                for (int c = 0; c < 4; ++c) O[ht][c] *= al;
        }
        __builtin_amdgcn_s_setprio(1);
        #pragma unroll
        for (int ks = 0; ks < 2; ++ks) {
            const int rcp = (ks * 4 + quad) * 8;          // Ps: NOT swizzled
            const int rcv = rcp ^ swr;                    // Vts: swizzled
            bf16x8 av[8];
            #pragma unroll
            for (int ht = 0; ht < 8; ++ht)
                av[ht] = *(const bf16x8*)&Vts[(ht * 16 + lane15) * 64 + rcv];
            bf16x8 bp = *(const bf16x8*)&Ps[(w * 16 + lane15) * 72 + rcp];
            #pragma unroll
            for (int ht = 0; ht < 8; ++ht)
                O[ht] = MFMA16(av[ht], bp, O[ht]);
        }
        __builtin_amdgcn_s_setprio(0);
    }

    // publish per-row denom (wave-private) and write out
    #pragma unroll
    for (int r = 0; r < 4; ++r)
        if (lane15 == r) Lrow[w * 16 + quad * 4 + r] = l_[r];
    __syncthreads();

    {
        const float linv = 1.0f / Lrow[w * 16 + lane15];
        const int s = q0 + w * 16 + lane15;
        #pragma unroll
        for (int ht = 0; ht < 8; ++ht) {
            bf16x4 o;
            #pragma unroll
            for (int c = 0; c < 4; ++c) o[c] = (bf16_t)(O[ht][c] * linv);
            *(bf16x4*)&CTX[((size_t)(b * Sc + s)) * HHDc + h * HDc + ht * 16 + quad * 4] = o;
        }
    }
}

// ---------------------------------------------------------------------------
// ws layout (bf16 element offsets; total exactly 134,217,728 B):
//   xb  bf16 [0,        8388608)   -> Kh after qkv_gemm (xb dead)
//   WT3 bf16 [8388608,  20971520)  -> Qh after qkv_gemm (WT3 dead)
//   WoT bf16 [20971520, 25165824)  (alive until final gemm)
//   Qf  fp32 [25165824, 41943040)  -> Vt after rope_scale_cast (Qf dead)
//   Kf  fp32 [41943040, 58720256)  -> CTX after rope_scale_cast (Kf dead)
//   Vb  bf16 [58720256, 67108864)
// ---------------------------------------------------------------------------
extern "C" void kernel_launch(void* const* d_in, const int* in_sizes, int n_in,
                              void* d_out, int out_size, void* d_ws, size_t ws_size,
                              hipStream_t stream)
{
    const float* x  = (const float*)d_in[0];
    const float* Wq = (const float*)d_in[2];
    const float* Wk = (const float*)d_in[3];
    const float* Wv = (const float*)d_in[4];
    const float* Wo = (const float*)d_in[5];
    float* out = (float*)d_out;

    bf16_t* W0  = (bf16_t*)d_ws;
    bf16_t* xb  = W0;
    bf16_t* WT3 = W0 + 8388608;
    bf16_t* WoT = W0 + 20971520;
    float*  Qf  = (float*)(W0 + 25165824);
    float*  Kf  = (float*)(W0 + 41943040);
    bf16_t* Vb  = W0 + 58720256;
    bf16_t* Kh  = W0;                     // alias: xb dead after qkv_gemm
    bf16_t* Qh  = W0 + 8388608;           // alias: WT3 dead after qkv_gemm
    bf16_t* Vt  = W0 + 25165824;          // alias: Qf dead after rope_scale_cast
    bf16_t* CTX = W0 + 41943040;          // alias: Kf dead after rope_scale_cast

    dim3 tw(32, 32);

    convert_x<<<8192, 256, 0, stream>>>(x, xb);
    transpose_w<<<tw, 256, 0, stream>>>(Wq, WT3);
    transpose_w<<<tw, 256, 0, stream>>>(Wk, WT3 + 4194304);
    transpose_w<<<tw, 256, 0, stream>>>(Wv, WT3 + 8388608);
    transpose_w<<<tw, 256, 0, stream>>>(Wo, WoT);

    qkv_gemm<<<dim3(48, 32), 256, 0, stream>>>(xb, WT3, Qf, Kf, Vb);

    rope_scale_cast<<<4096, 256, 0, stream>>>(Qf, Kf, Qh, Kh);
    prep_vtb<<<dim3(32, 2, 32), 256, 0, stream>>>(Vb, Vt);

    attn_v5<<<dim3(16, 32), 512, 0, stream>>>(Qh, Kh, Vt, CTX);

    gemm_bt<<<dim3(16, 32), 256, 0, stream>>>(CTX, WoT, out);
}

// Round 4
// 478.359 us; speedup vs baseline: 1.3413x; 1.0707x over previous
//
#include <hip/hip_runtime.h>
#include <math.h>

// (B,S,D,H,HD) = (2,2048,2048,16,128)
#define Bc   2
#define Sc   2048
#define Dc   2048
#define Hc   16
#define HDc  128
#define BSc  4096
#define HHDc 2048

typedef __bf16 bf16_t;
typedef __bf16 bf16x8 __attribute__((ext_vector_type(8)));
typedef __bf16 bf16x4 __attribute__((ext_vector_type(4)));
typedef float  f32x4  __attribute__((ext_vector_type(4)));

#define AS1(p) ((const __attribute__((address_space(1))) void*)(p))
#define AS3(p) ((__attribute__((address_space(3))) void*)(p))

#define MFMA16(a,b,c) __builtin_amdgcn_mfma_f32_16x16x32_bf16((a),(b),(c),0,0,0)

// ---------------------------------------------------------------------------
// x: fp32 -> bf16 (same layout)  [verified]
// ---------------------------------------------------------------------------
__global__ void convert_x(const float* __restrict__ x, bf16_t* __restrict__ xb)
{
    const size_t i = ((size_t)blockIdx.x * 256 + threadIdx.x) * 4;
    float4 v = *(const float4*)&x[i];
    bf16x4 o; o[0]=(bf16_t)v.x; o[1]=(bf16_t)v.y; o[2]=(bf16_t)v.z; o[3]=(bf16_t)v.w;
    *(bf16x4*)&xb[i] = o;
}

// ---------------------------------------------------------------------------
// W [K=2048][N=2048] fp32 -> W^T [N][K] bf16  [verified]
// ---------------------------------------------------------------------------
__global__ __launch_bounds__(256) void transpose_w(const float* __restrict__ in,
                                                   bf16_t* __restrict__ out)
{
    __shared__ float T[64][65];
    const int t = threadIdx.x;
    const int r0 = blockIdx.y * 64, c0 = blockIdx.x * 64;
    #pragma unroll
    for (int i = 0; i < 4; ++i) {
        int row = i * 16 + (t >> 4);
        int c4  = (t & 15) * 4;
        float4 v = *(const float4*)&in[(size_t)(r0 + row) * 2048 + c0 + c4];
        T[row][c4] = v.x; T[row][c4+1] = v.y; T[row][c4+2] = v.z; T[row][c4+3] = v.w;
    }
    __syncthreads();
    #pragma unroll
    for (int i = 0; i < 4; ++i) {
        int orow = i * 16 + (t >> 4);
        int c4   = (t & 15) * 4;
        bf16x4 o;
        #pragma unroll
        for (int j = 0; j < 4; ++j) o[j] = (bf16_t)T[c4 + j][orow];
        *(bf16x4*)&out[(size_t)(c0 + orow) * 2048 + r0 + c4] = o;
    }
}

// ---------------------------------------------------------------------------
// bf16 V [b*S+s][h*128+hd] -> bf16 V^T [bh][hd][s]  (transpose_w pattern)
// ---------------------------------------------------------------------------
__global__ __launch_bounds__(256) void prep_vtb(const bf16_t* __restrict__ V,
                                                bf16_t* __restrict__ Vt)
{
    __shared__ float T[64][65];
    const int t = threadIdx.x;
    const int s0 = blockIdx.x * 64;
    const int c0 = blockIdx.y * 64;          // hd tile (0 or 64)
    const int bh = blockIdx.z;
    const int b = bh >> 4, h = bh & 15;
    #pragma unroll
    for (int i = 0; i < 4; ++i) {
        int row = i * 16 + (t >> 4);         // s-local
        int c4  = (t & 15) * 4;              // hd-local
        bf16x4 v = *(const bf16x4*)&V[((size_t)(b * Sc + s0 + row)) * HHDc + h * HDc + c0 + c4];
        #pragma unroll
        for (int j = 0; j < 4; ++j) T[row][c4 + j] = (float)v[j];
    }
    __syncthreads();
    #pragma unroll
    for (int i = 0; i < 4; ++i) {
        int orow = i * 16 + (t >> 4);        // hd-local
        int c4   = (t & 15) * 4;             // s-local
        bf16x4 o;
        #pragma unroll
        for (int j = 0; j < 4; ++j) o[j] = (bf16_t)T[c4 + j][orow];
        *(bf16x4*)&Vt[((size_t)bh * HDc + c0 + orow) * Sc + s0 + c4] = o;
    }
}

// ---------------------------------------------------------------------------
// Fused QKV GEMM: C[4096][6144] = xb * WT3^T; gemm_bt inner loop + T2
// XOR-swizzle: LDS[row][c] = global[row][c ^ ((row&7)*8)] via inverse-
// swizzled global source col (global_load_lds writes linearly, rule #21);
// reads use rc ^ (lane15&7)*8 (row&7 == lane15&7 for all fragment reads).
// Output router: n<2048 -> Qf fp32; n<4096 -> Kf fp32; else -> Vb bf16.
// ---------------------------------------------------------------------------
__global__ __launch_bounds__(256) void qkv_gemm(const bf16_t* __restrict__ A,
                                                const bf16_t* __restrict__ Bt,
                                                float* __restrict__ Qf,
                                                float* __restrict__ Kf,
                                                bf16_t* __restrict__ Vb)
{
    __shared__ bf16_t As[128 * 64];
    __shared__ bf16_t Bs[128 * 64];
    const int t = threadIdx.x;
    const int w = t >> 6, l = t & 63;
    const int wm = w >> 1, wn = w & 1;
    const int lane15 = l & 15, quad = l >> 4;
    const int swr = (lane15 & 7) * 8;        // read-side column swizzle
    const int m0 = blockIdx.y * 128, n0 = blockIdx.x * 128;

    f32x4 acc[4][4];
    #pragma unroll
    for (int i = 0; i < 4; ++i)
        #pragma unroll
        for (int j = 0; j < 4; ++j)
            #pragma unroll
            for (int c = 0; c < 4; ++c) acc[i][j][c] = 0.f;

    const int srow = w * 8 + (l >> 3);
    const int gk   = ((l & 7) * 8) ^ ((srow & 7) * 8);   // inverse-swizzled src col

    for (int k0 = 0; k0 < 2048; k0 += 64) {
        __syncthreads();
        #pragma unroll
        for (int p = 0; p < 4; ++p) {
            __builtin_amdgcn_global_load_lds(
                AS1(A + (size_t)(m0 + p * 32 + srow) * 2048 + k0 + gk),
                AS3(&As[(p * 32 + w * 8) * 64]), 16, 0, 0);
            __builtin_amdgcn_global_load_lds(
                AS1(Bt + (size_t)(n0 + p * 32 + srow) * 2048 + k0 + gk),
                AS3(&Bs[(p * 32 + w * 8) * 64]), 16, 0, 0);
        }
        __syncthreads();
        #pragma unroll
        for (int ks = 0; ks < 2; ++ks) {
            const int rc = ((ks * 4 + quad) * 8) ^ swr;
            bf16x8 a[4], b[4];
            #pragma unroll
            for (int mt = 0; mt < 4; ++mt)
                a[mt] = *(const bf16x8*)&As[(wm * 64 + mt * 16 + lane15) * 64 + rc];
            #pragma unroll
            for (int nt = 0; nt < 4; ++nt)
                b[nt] = *(const bf16x8*)&Bs[(wn * 64 + nt * 16 + lane15) * 64 + rc];
            #pragma unroll
            for (int mt = 0; mt < 4; ++mt)
                #pragma unroll
                for (int nt = 0; nt < 4; ++nt)
                    acc[mt][nt] = MFMA16(a[mt], b[nt], acc[mt][nt]);
        }
    }

    if (n0 < 4096) {
        float* __restrict__ dst = (n0 < 2048) ? Qf : Kf;
        const int nb = n0 & 2047;
        #pragma unroll
        for (int mt = 0; mt < 4; ++mt)
            #pragma unroll
            for (int nt = 0; nt < 4; ++nt)
                #pragma unroll
                for (int r = 0; r < 4; ++r) {
                    const int gm = m0 + wm * 64 + mt * 16 + quad * 4 + r;
                    const int gn = nb + wn * 64 + nt * 16 + lane15;
                    dst[(size_t)gm * 2048 + gn] = acc[mt][nt][r];
                }
    } else {
        const int nb = n0 - 4096;
        #pragma unroll
        for (int mt = 0; mt < 4; ++mt)
            #pragma unroll
            for (int nt = 0; nt < 4; ++nt)
                #pragma unroll
                for (int r = 0; r < 4; ++r) {
                    const int gm = m0 + wm * 64 + mt * 16 + quad * 4 + r;
                    const int gn = nb + wn * 64 + nt * 16 + lane15;
                    Vb[(size_t)gm * 2048 + gn] = (bf16_t)acc[mt][nt][r];
                }
    }
}

// ---------------------------------------------------------------------------
// GEMM: C[4096][2048] = A * Bt^T, bf16 in fp32 out (final proj) + T2 swizzle
// ---------------------------------------------------------------------------
__global__ __launch_bounds__(256) void gemm_bt(const bf16_t* __restrict__ A,
                                               const bf16_t* __restrict__ Bt,
                                               float* __restrict__ C)
{
    __shared__ bf16_t As[128 * 64];
    __shared__ bf16_t Bs[128 * 64];
    const int t = threadIdx.x;
    const int w = t >> 6, l = t & 63;
    const int wm = w >> 1, wn = w & 1;
    const int lane15 = l & 15, quad = l >> 4;
    const int swr = (lane15 & 7) * 8;
    const int m0 = blockIdx.y * 128, n0 = blockIdx.x * 128;

    f32x4 acc[4][4];
    #pragma unroll
    for (int i = 0; i < 4; ++i)
        #pragma unroll
        for (int j = 0; j < 4; ++j)
            #pragma unroll
            for (int c = 0; c < 4; ++c) acc[i][j][c] = 0.f;

    const int srow = w * 8 + (l >> 3);
    const int gk   = ((l & 7) * 8) ^ ((srow & 7) * 8);

    for (int k0 = 0; k0 < 2048; k0 += 64) {
        __syncthreads();
        #pragma unroll
        for (int p = 0; p < 4; ++p) {
            __builtin_amdgcn_global_load_lds(
                AS1(A + (size_t)(m0 + p * 32 + srow) * 2048 + k0 + gk),
                AS3(&As[(p * 32 + w * 8) * 64]), 16, 0, 0);
            __builtin_amdgcn_global_load_lds(
                AS1(Bt + (size_t)(n0 + p * 32 + srow) * 2048 + k0 + gk),
                AS3(&Bs[(p * 32 + w * 8) * 64]), 16, 0, 0);
        }
        __syncthreads();
        #pragma unroll
        for (int ks = 0; ks < 2; ++ks) {
            const int rc = ((ks * 4 + quad) * 8) ^ swr;
            bf16x8 a[4], b[4];
            #pragma unroll
            for (int mt = 0; mt < 4; ++mt)
                a[mt] = *(const bf16x8*)&As[(wm * 64 + mt * 16 + lane15) * 64 + rc];
            #pragma unroll
            for (int nt = 0; nt < 4; ++nt)
                b[nt] = *(const bf16x8*)&Bs[(wn * 64 + nt * 16 + lane15) * 64 + rc];
            #pragma unroll
            for (int mt = 0; mt < 4; ++mt)
                #pragma unroll
                for (int nt = 0; nt < 4; ++nt)
                    acc[mt][nt] = MFMA16(a[mt], b[nt], acc[mt][nt]);
        }
    }

    #pragma unroll
    for (int mt = 0; mt < 4; ++mt)
        #pragma unroll
        for (int nt = 0; nt < 4; ++nt)
            #pragma unroll
            for (int r = 0; r < 4; ++r) {
                const int gm = m0 + wm * 64 + mt * 16 + quad * 4 + r;
                const int gn = n0 + wn * 64 + nt * 16 + lane15;
                C[(size_t)gm * 2048 + gn] = acc[mt][nt][r];
            }
}

// ---------------------------------------------------------------------------
// Fused RoPE + scale + bf16 cast: read Qf/Kf fp32, write Qh (scaled)/Kh bf16.
// ---------------------------------------------------------------------------
__global__ void rope_scale_cast(const float* __restrict__ Qf,
                                const float* __restrict__ Kf,
                                bf16_t* __restrict__ Qh,
                                bf16_t* __restrict__ Kh)
{
    const int idx  = blockIdx.x * 256 + threadIdx.x;   // 1,048,576 total
    const int j4   = (idx & 15) * 4;                   // 0..60
    const int h    = (idx >> 4) & (Hc - 1);
    const int sabs = idx >> 8;
    const int s    = sabs & (Sc - 1);
    const float QS = 0.08838834764831845f;

    const size_t base = (size_t)sabs * HHDc + (size_t)h * HDc + j4;
    float4 q1 = *(const float4*)&Qf[base];
    float4 q2 = *(const float4*)&Qf[base + 64];
    float4 k1 = *(const float4*)&Kf[base];
    float4 k2 = *(const float4*)&Kf[base + 64];

    bf16x4 qo1, qo2, ko1, ko2;
    #pragma unroll
    for (int c = 0; c < 4; ++c) {
        const float freq = expf(-(float)(j4 + c) * 0.14391156514261520f);
        const float ang  = (float)s * freq;
        float sn, cs;
        sincosf(ang, &sn, &cs);
        const float a = ((const float*)&q1)[c], bq = ((const float*)&q2)[c];
        const float x = ((const float*)&k1)[c], y  = ((const float*)&k2)[c];
        qo1[c] = (bf16_t)((a * cs - bq * sn) * QS);
        qo2[c] = (bf16_t)((bq * cs + a * sn) * QS);
        ko1[c] = (bf16_t)(x * cs - y * sn);
        ko2[c] = (bf16_t)(y * cs + x * sn);
    }
    *(bf16x4*)&Qh[base]      = qo1;
    *(bf16x4*)&Qh[base + 64] = qo2;
    *(bf16x4*)&Kh[base]      = ko1;
    *(bf16x4*)&Kh[base + 64] = ko2;
}

// ---------------------------------------------------------------------------
// attn_v6: v5 + T14 async-STAGE split. K/V tiles are reg-staged:
//   tile kt: barrier -> ds_write regs (swizzled col, same LDS image as v5)
//            -> issue global loads for kt+1 -> barrier -> compute.
// No vmcnt(0) drain between barriers; HBM latency for kt+1 hides under
// tile kt's QK^T + softmax + PV. Read side identical to v5.
// ---------------------------------------------------------------------------
__global__ __launch_bounds__(512, 4) void attn_v6(const bf16_t* __restrict__ Q,
                                                  const bf16_t* __restrict__ K,
                                                  const bf16_t* __restrict__ Vt,
                                                  bf16_t* __restrict__ CTX)
{
    __shared__ bf16_t Ks[64 * 128];    // [k_local][hd]   (col-swizzled)
    __shared__ bf16_t Vts[128 * 64];   // [hd][key_local] (col-swizzled)
    __shared__ bf16_t Ps[128 * 72];    // bf16 P[q][key], wave-private rows
    __shared__ float  Arow[128];       // per-tile alpha, wave-private rows
    __shared__ float  Lrow[128];       // final denom, wave-private rows

    const int t = threadIdx.x, w = t >> 6, l = t & 63;
    const int lane15 = l & 15, quad = l >> 4;
    const int swr = (lane15 & 7) * 8;          // read-side column swizzle
    const int q0 = blockIdx.x * 128;
    const int b = blockIdx.y >> 4, h = blockIdx.y & 15;
    const size_t qbase = ((size_t)(b * Sc + q0)) * HHDc + h * HDc;
    const size_t vtb   = (size_t)blockIdx.y * HDc * Sc;
    const size_t kb0   = ((size_t)(b * Sc)) * HHDc + h * HDc;

    // ---- Q fragments straight to registers (wave owns 16 q-rows) ----
    bf16x8 qf[4];
    #pragma unroll
    for (int ks = 0; ks < 4; ++ks)
        qf[ks] = *(const bf16x8*)&Q[qbase
            + (size_t)(w * 16 + lane15) * HHDc + (ks * 4 + quad) * 8];

    // online-softmax state per owned q-row r (qrow = w*16+quad*4+r)
    float m_[4], l_[4];
    #pragma unroll
    for (int r = 0; r < 4; ++r) { m_[r] = -INFINITY; l_[r] = 0.f; }

    f32x4 O[8];        // PV acc: O[ht], hd=ht*16+quad*4+c, q=w*16+lane15
    #pragma unroll
    for (int i = 0; i < 8; ++i)
        #pragma unroll
        for (int c = 0; c < 4; ++c) O[i][c] = 0.f;

    // staging geometry (per thread)
    const int krow0 = w * 4 + (l >> 4);      // + p*32 ; K row (key index)
    const int kgc   = lane15 * 8;            // K global col (linear)
    const int vrow0 = w * 8 + (l >> 3);      // + p*64 ; Vt row (hd index)
    const int vgc   = (l & 7) * 8;           // Vt global col within tile

    bf16x8 kst[2], vst[2];
    // prologue: load tile 0 into registers
    #pragma unroll
    for (int p = 0; p < 2; ++p) {
        kst[p] = *(const bf16x8*)&K[kb0 + (size_t)(p * 32 + krow0) * HHDc + kgc];
        vst[p] = *(const bf16x8*)&Vt[vtb + (size_t)(p * 64 + vrow0) * Sc + vgc];
    }

    for (int kt = 0; kt < Sc / 64; ++kt) {
        __syncthreads();   // prev tile's readers done; Ks/Vts free
        // ---- write staged regs to LDS with swizzled column ----
        #pragma unroll
        for (int p = 0; p < 2; ++p) {
            const int rk = p * 32 + krow0;
            *(bf16x8*)&Ks[rk * 128 + (kgc ^ ((rk & 7) * 8))] = kst[p];
        }
        #pragma unroll
        for (int p = 0; p < 2; ++p) {
            const int rv = p * 64 + vrow0;
            *(bf16x8*)&Vts[rv * 64 + (vgc ^ ((rv & 7) * 8))] = vst[p];
        }
        // ---- issue next tile's global loads (hidden under compute) ----
        if (kt + 1 < Sc / 64) {
            const size_t kbn = kb0 + (size_t)(kt + 1) * 64 * HHDc;
            #pragma unroll
            for (int p = 0; p < 2; ++p) {
                kst[p] = *(const bf16x8*)&K[kbn + (size_t)(p * 32 + krow0) * HHDc + kgc];
                vst[p] = *(const bf16x8*)&Vt[vtb + (size_t)(p * 64 + vrow0) * Sc
                                             + (kt + 1) * 64 + vgc];
            }
        }
        __syncthreads();   // Ks/Vts ready for all waves

        // ---- MFMA QK^T: wave w owns q-rows w*16..w*16+15, all 64 keys ----
        f32x4 sc[4];
        #pragma unroll
        for (int j = 0; j < 4; ++j)
            #pragma unroll
            for (int c = 0; c < 4; ++c) sc[j][c] = 0.f;
        __builtin_amdgcn_s_setprio(1);
        #pragma unroll
        for (int ks = 0; ks < 4; ++ks) {
            const int rc = ((ks * 4 + quad) * 8) ^ swr;   // swizzled column
            bf16x8 bk[4];
            #pragma unroll
            for (int nt = 0; nt < 4; ++nt)
                bk[nt] = *(const bf16x8*)&Ks[(nt * 16 + lane15) * 128 + rc];
            #pragma unroll
            for (int nt = 0; nt < 4; ++nt)
                sc[nt] = MFMA16(qf[ks], bk[nt], sc[nt]);
        }
        __builtin_amdgcn_s_setprio(0);

        // ---- in-register online softmax (4 owned q-rows per thread) ----
        #pragma unroll
        for (int r = 0; r < 4; ++r) {
            const float v0 = sc[0][r], v1 = sc[1][r];
            const float v2 = sc[2][r], v3 = sc[3][r];
            float tm = fmaxf(fmaxf(v0, v1), fmaxf(v2, v3));
            tm = fmaxf(tm, __shfl_xor(tm, 1));
            tm = fmaxf(tm, __shfl_xor(tm, 2));
            tm = fmaxf(tm, __shfl_xor(tm, 4));
            tm = fmaxf(tm, __shfl_xor(tm, 8));
            const float mo = m_[r];
            const float mn = fmaxf(mo, tm);
            const float al = __expf(mo - mn);
            m_[r] = mn;
            const float p0 = __expf(v0 - mn), p1 = __expf(v1 - mn);
            const float p2 = __expf(v2 - mn), p3 = __expf(v3 - mn);
            float ts = (p0 + p1) + (p2 + p3);
            ts += __shfl_xor(ts, 1);
            ts += __shfl_xor(ts, 2);
            ts += __shfl_xor(ts, 4);
            ts += __shfl_xor(ts, 8);
            l_[r] = l_[r] * al + ts;
            const int qrow = w * 16 + quad * 4 + r;
            Ps[qrow * 72 +  0 + lane15] = (bf16_t)p0;
            Ps[qrow * 72 + 16 + lane15] = (bf16_t)p1;
            Ps[qrow * 72 + 32 + lane15] = (bf16_t)p2;
            Ps[qrow * 72 + 48 + lane15] = (bf16_t)p3;
            if (lane15 == r) Arow[qrow] = al;
        }
        // Ps/Arow are wave-private: wave-synchronous exec + lgkmcnt ordering
        // make a block barrier unnecessary before the PV reads below.

        // ---- MFMA PV: rescale O by alpha(q), then ctx^T += V^T P^T ----
        {
            const float al = Arow[w * 16 + lane15];
            #pragma unroll
            for (int ht = 0; ht < 8; ++ht)
                #pragma unroll
                for (int c = 0; c < 4; ++c) O[ht][c] *= al;
        }
        __builtin_amdgcn_s_setprio(1);
        #pragma unroll
        for (int ks = 0; ks < 2; ++ks) {
            const int rcp = (ks * 4 + quad) * 8;          // Ps: NOT swizzled
            const int rcv = rcp ^ swr;                    // Vts: swizzled
            bf16x8 av[8];
            #pragma unroll
            for (int ht = 0; ht < 8; ++ht)
                av[ht] = *(const bf16x8*)&Vts[(ht * 16 + lane15) * 64 + rcv];
            bf16x8 bp = *(const bf16x8*)&Ps[(w * 16 + lane15) * 72 + rcp];
            #pragma unroll
            for (int ht = 0; ht < 8; ++ht)
                O[ht] = MFMA16(av[ht], bp, O[ht]);
        }
        __builtin_amdgcn_s_setprio(0);
    }

    // publish per-row denom (wave-private) and write out
    #pragma unroll
    for (int r = 0; r < 4; ++r)
        if (lane15 == r) Lrow[w * 16 + quad * 4 + r] = l_[r];
    __syncthreads();

    {
        const float linv = 1.0f / Lrow[w * 16 + lane15];
        const int s = q0 + w * 16 + lane15;
        #pragma unroll
        for (int ht = 0; ht < 8; ++ht) {
            bf16x4 o;
            #pragma unroll
            for (int c = 0; c < 4; ++c) o[c] = (bf16_t)(O[ht][c] * linv);
            *(bf16x4*)&CTX[((size_t)(b * Sc + s)) * HHDc + h * HDc + ht * 16 + quad * 4] = o;
        }
    }
}

// ---------------------------------------------------------------------------
// ws layout (bf16 element offsets; total exactly 134,217,728 B):
//   xb  bf16 [0,        8388608)   -> Kh after qkv_gemm (xb dead)
//   WT3 bf16 [8388608,  20971520)  -> Qh after qkv_gemm (WT3 dead)
//   WoT bf16 [20971520, 25165824)  (alive until final gemm)
//   Qf  fp32 [25165824, 41943040)  -> Vt after rope_scale_cast (Qf dead)
//   Kf  fp32 [41943040, 58720256)  -> CTX after rope_scale_cast (Kf dead)
//   Vb  bf16 [58720256, 67108864)
// ---------------------------------------------------------------------------
extern "C" void kernel_launch(void* const* d_in, const int* in_sizes, int n_in,
                              void* d_out, int out_size, void* d_ws, size_t ws_size,
                              hipStream_t stream)
{
    const float* x  = (const float*)d_in[0];
    const float* Wq = (const float*)d_in[2];
    const float* Wk = (const float*)d_in[3];
    const float* Wv = (const float*)d_in[4];
    const float* Wo = (const float*)d_in[5];
    float* out = (float*)d_out;

    bf16_t* W0  = (bf16_t*)d_ws;
    bf16_t* xb  = W0;
    bf16_t* WT3 = W0 + 8388608;
    bf16_t* WoT = W0 + 20971520;
    float*  Qf  = (float*)(W0 + 25165824);
    float*  Kf  = (float*)(W0 + 41943040);
    bf16_t* Vb  = W0 + 58720256;
    bf16_t* Kh  = W0;                     // alias: xb dead after qkv_gemm
    bf16_t* Qh  = W0 + 8388608;           // alias: WT3 dead after qkv_gemm
    bf16_t* Vt  = W0 + 25165824;          // alias: Qf dead after rope_scale_cast
    bf16_t* CTX = W0 + 41943040;          // alias: Kf dead after rope_scale_cast

    dim3 tw(32, 32);

    convert_x<<<8192, 256, 0, stream>>>(x, xb);
    transpose_w<<<tw, 256, 0, stream>>>(Wq, WT3);
    transpose_w<<<tw, 256, 0, stream>>>(Wk, WT3 + 4194304);
    transpose_w<<<tw, 256, 0, stream>>>(Wv, WT3 + 8388608);
    transpose_w<<<tw, 256, 0, stream>>>(Wo, WoT);

    qkv_gemm<<<dim3(48, 32), 256, 0, stream>>>(xb, WT3, Qf, Kf, Vb);

    rope_scale_cast<<<4096, 256, 0, stream>>>(Qf, Kf, Qh, Kh);
    prep_vtb<<<dim3(32, 2, 32), 256, 0, stream>>>(Vb, Vt);

    attn_v6<<<dim3(16, 32), 512, 0, stream>>>(Qh, Kh, Vt, CTX);

    gemm_bt<<<dim3(16, 32), 256, 0, stream>>>(CTX, WoT, out);
}

// Round 5
// 441.276 us; speedup vs baseline: 1.4540x; 1.0840x over previous
//
#include <hip/hip_runtime.h>
#include <math.h>

// (B,S,D,H,HD) = (2,2048,2048,16,128)
#define Bc   2
#define Sc   2048
#define Dc   2048
#define Hc   16
#define HDc  128
#define BSc  4096
#define HHDc 2048

typedef __bf16 bf16_t;
typedef __bf16 bf16x8 __attribute__((ext_vector_type(8)));
typedef __bf16 bf16x4 __attribute__((ext_vector_type(4)));
typedef float  f32x4  __attribute__((ext_vector_type(4)));

#define AS1(p) ((const __attribute__((address_space(1))) void*)(p))
#define AS3(p) ((__attribute__((address_space(3))) void*)(p))

#define MFMA16(a,b,c) __builtin_amdgcn_mfma_f32_16x16x32_bf16((a),(b),(c),0,0,0)

// ---------------------------------------------------------------------------
// x: fp32 -> bf16 (same layout)  [verified]
// ---------------------------------------------------------------------------
__global__ void convert_x(const float* __restrict__ x, bf16_t* __restrict__ xb)
{
    const size_t i = ((size_t)blockIdx.x * 256 + threadIdx.x) * 4;
    float4 v = *(const float4*)&x[i];
    bf16x4 o; o[0]=(bf16_t)v.x; o[1]=(bf16_t)v.y; o[2]=(bf16_t)v.z; o[3]=(bf16_t)v.w;
    *(bf16x4*)&xb[i] = o;
}

// ---------------------------------------------------------------------------
// W [K=2048][N=2048] fp32 -> W^T [N][K] bf16  [verified]
// ---------------------------------------------------------------------------
__global__ __launch_bounds__(256) void transpose_w(const float* __restrict__ in,
                                                   bf16_t* __restrict__ out)
{
    __shared__ float T[64][65];
    const int t = threadIdx.x;
    const int r0 = blockIdx.y * 64, c0 = blockIdx.x * 64;
    #pragma unroll
    for (int i = 0; i < 4; ++i) {
        int row = i * 16 + (t >> 4);
        int c4  = (t & 15) * 4;
        float4 v = *(const float4*)&in[(size_t)(r0 + row) * 2048 + c0 + c4];
        T[row][c4] = v.x; T[row][c4+1] = v.y; T[row][c4+2] = v.z; T[row][c4+3] = v.w;
    }
    __syncthreads();
    #pragma unroll
    for (int i = 0; i < 4; ++i) {
        int orow = i * 16 + (t >> 4);
        int c4   = (t & 15) * 4;
        bf16x4 o;
        #pragma unroll
        for (int j = 0; j < 4; ++j) o[j] = (bf16_t)T[c4 + j][orow];
        *(bf16x4*)&out[(size_t)(c0 + orow) * 2048 + r0 + c4] = o;
    }
}

// ---------------------------------------------------------------------------
// bf16 V [b*S+s][h*128+hd] -> bf16 V^T [bh][hd][s]  (transpose_w pattern)
// ---------------------------------------------------------------------------
__global__ __launch_bounds__(256) void prep_vtb(const bf16_t* __restrict__ V,
                                                bf16_t* __restrict__ Vt)
{
    __shared__ float T[64][65];
    const int t = threadIdx.x;
    const int s0 = blockIdx.x * 64;
    const int c0 = blockIdx.y * 64;          // hd tile (0 or 64)
    const int bh = blockIdx.z;
    const int b = bh >> 4, h = bh & 15;
    #pragma unroll
    for (int i = 0; i < 4; ++i) {
        int row = i * 16 + (t >> 4);         // s-local
        int c4  = (t & 15) * 4;              // hd-local
        bf16x4 v = *(const bf16x4*)&V[((size_t)(b * Sc + s0 + row)) * HHDc + h * HDc + c0 + c4];
        #pragma unroll
        for (int j = 0; j < 4; ++j) T[row][c4 + j] = (float)v[j];
    }
    __syncthreads();
    #pragma unroll
    for (int i = 0; i < 4; ++i) {
        int orow = i * 16 + (t >> 4);        // hd-local
        int c4   = (t & 15) * 4;             // s-local
        bf16x4 o;
        #pragma unroll
        for (int j = 0; j < 4; ++j) o[j] = (bf16_t)T[c4 + j][orow];
        *(bf16x4*)&Vt[((size_t)bh * HDc + c0 + orow) * Sc + s0 + c4] = o;
    }
}

// ---------------------------------------------------------------------------
// Fused QKV GEMM: C[4096][6144] = xb * WT3^T; T2-swizzled LDS + T1 XCD
// swizzle (grid 48x32 = 1536 wg, 1536%8==0 -> simple bijective remap; each
// XCD chunk = 4 consecutive m-rows -> 2MB of A panels L2-resident).
// Output router: n<2048 -> Qf fp32; n<4096 -> Kf fp32; else -> Vb bf16.
// ---------------------------------------------------------------------------
__global__ __launch_bounds__(256) void qkv_gemm(const bf16_t* __restrict__ A,
                                                const bf16_t* __restrict__ Bt,
                                                float* __restrict__ Qf,
                                                float* __restrict__ Kf,
                                                bf16_t* __restrict__ Vb)
{
    __shared__ bf16_t As[128 * 64];
    __shared__ bf16_t Bs[128 * 64];
    const int t = threadIdx.x;
    const int w = t >> 6, l = t & 63;
    const int wm = w >> 1, wn = w & 1;
    const int lane15 = l & 15, quad = l >> 4;
    const int swr = (lane15 & 7) * 8;        // read-side column swizzle

    // T1: XCD-aware block swizzle (flattened id, x fastest; 1536/8 = 192)
    const int id  = blockIdx.y * 48 + blockIdx.x;
    const int swz = (id & 7) * 192 + (id >> 3);
    const int m0 = (swz / 48) * 128, n0 = (swz % 48) * 128;

    f32x4 acc[4][4];
    #pragma unroll
    for (int i = 0; i < 4; ++i)
        #pragma unroll
        for (int j = 0; j < 4; ++j)
            #pragma unroll
            for (int c = 0; c < 4; ++c) acc[i][j][c] = 0.f;

    const int srow = w * 8 + (l >> 3);
    const int gk   = ((l & 7) * 8) ^ ((srow & 7) * 8);   // inverse-swizzled src col

    for (int k0 = 0; k0 < 2048; k0 += 64) {
        __syncthreads();
        #pragma unroll
        for (int p = 0; p < 4; ++p) {
            __builtin_amdgcn_global_load_lds(
                AS1(A + (size_t)(m0 + p * 32 + srow) * 2048 + k0 + gk),
                AS3(&As[(p * 32 + w * 8) * 64]), 16, 0, 0);
            __builtin_amdgcn_global_load_lds(
                AS1(Bt + (size_t)(n0 + p * 32 + srow) * 2048 + k0 + gk),
                AS3(&Bs[(p * 32 + w * 8) * 64]), 16, 0, 0);
        }
        __syncthreads();
        #pragma unroll
        for (int ks = 0; ks < 2; ++ks) {
            const int rc = ((ks * 4 + quad) * 8) ^ swr;
            bf16x8 a[4], b[4];
            #pragma unroll
            for (int mt = 0; mt < 4; ++mt)
                a[mt] = *(const bf16x8*)&As[(wm * 64 + mt * 16 + lane15) * 64 + rc];
            #pragma unroll
            for (int nt = 0; nt < 4; ++nt)
                b[nt] = *(const bf16x8*)&Bs[(wn * 64 + nt * 16 + lane15) * 64 + rc];
            #pragma unroll
            for (int mt = 0; mt < 4; ++mt)
                #pragma unroll
                for (int nt = 0; nt < 4; ++nt)
                    acc[mt][nt] = MFMA16(a[mt], b[nt], acc[mt][nt]);
        }
    }

    if (n0 < 4096) {
        float* __restrict__ dst = (n0 < 2048) ? Qf : Kf;
        const int nb = n0 & 2047;
        #pragma unroll
        for (int mt = 0; mt < 4; ++mt)
            #pragma unroll
            for (int nt = 0; nt < 4; ++nt)
                #pragma unroll
                for (int r = 0; r < 4; ++r) {
                    const int gm = m0 + wm * 64 + mt * 16 + quad * 4 + r;
                    const int gn = nb + wn * 64 + nt * 16 + lane15;
                    dst[(size_t)gm * 2048 + gn] = acc[mt][nt][r];
                }
    } else {
        const int nb = n0 - 4096;
        #pragma unroll
        for (int mt = 0; mt < 4; ++mt)
            #pragma unroll
            for (int nt = 0; nt < 4; ++nt)
                #pragma unroll
                for (int r = 0; r < 4; ++r) {
                    const int gm = m0 + wm * 64 + mt * 16 + quad * 4 + r;
                    const int gn = nb + wn * 64 + nt * 16 + lane15;
                    Vb[(size_t)gm * 2048 + gn] = (bf16_t)acc[mt][nt][r];
                }
    }
}

// ---------------------------------------------------------------------------
// GEMM: C[4096][2048] = A * Bt^T (final proj) + T2 swizzle + T1 XCD swizzle
// ---------------------------------------------------------------------------
__global__ __launch_bounds__(256) void gemm_bt(const bf16_t* __restrict__ A,
                                               const bf16_t* __restrict__ Bt,
                                               float* __restrict__ C)
{
    __shared__ bf16_t As[128 * 64];
    __shared__ bf16_t Bs[128 * 64];
    const int t = threadIdx.x;
    const int w = t >> 6, l = t & 63;
    const int wm = w >> 1, wn = w & 1;
    const int lane15 = l & 15, quad = l >> 4;
    const int swr = (lane15 & 7) * 8;

    // T1: XCD swizzle (grid 16x32 = 512 wg, 512/8 = 64)
    const int id  = blockIdx.y * 16 + blockIdx.x;
    const int swz = (id & 7) * 64 + (id >> 3);
    const int m0 = (swz / 16) * 128, n0 = (swz % 16) * 128;

    f32x4 acc[4][4];
    #pragma unroll
    for (int i = 0; i < 4; ++i)
        #pragma unroll
        for (int j = 0; j < 4; ++j)
            #pragma unroll
            for (int c = 0; c < 4; ++c) acc[i][j][c] = 0.f;

    const int srow = w * 8 + (l >> 3);
    const int gk   = ((l & 7) * 8) ^ ((srow & 7) * 8);

    for (int k0 = 0; k0 < 2048; k0 += 64) {
        __syncthreads();
        #pragma unroll
        for (int p = 0; p < 4; ++p) {
            __builtin_amdgcn_global_load_lds(
                AS1(A + (size_t)(m0 + p * 32 + srow) * 2048 + k0 + gk),
                AS3(&As[(p * 32 + w * 8) * 64]), 16, 0, 0);
            __builtin_amdgcn_global_load_lds(
                AS1(Bt + (size_t)(n0 + p * 32 + srow) * 2048 + k0 + gk),
                AS3(&Bs[(p * 32 + w * 8) * 64]), 16, 0, 0);
        }
        __syncthreads();
        #pragma unroll
        for (int ks = 0; ks < 2; ++ks) {
            const int rc = ((ks * 4 + quad) * 8) ^ swr;
            bf16x8 a[4], b[4];
            #pragma unroll
            for (int mt = 0; mt < 4; ++mt)
                a[mt] = *(const bf16x8*)&As[(wm * 64 + mt * 16 + lane15) * 64 + rc];
            #pragma unroll
            for (int nt = 0; nt < 4; ++nt)
                b[nt] = *(const bf16x8*)&Bs[(wn * 64 + nt * 16 + lane15) * 64 + rc];
            #pragma unroll
            for (int mt = 0; mt < 4; ++mt)
                #pragma unroll
                for (int nt = 0; nt < 4; ++nt)
                    acc[mt][nt] = MFMA16(a[mt], b[nt], acc[mt][nt]);
        }
    }

    #pragma unroll
    for (int mt = 0; mt < 4; ++mt)
        #pragma unroll
        for (int nt = 0; nt < 4; ++nt)
            #pragma unroll
            for (int r = 0; r < 4; ++r) {
                const int gm = m0 + wm * 64 + mt * 16 + quad * 4 + r;
                const int gn = n0 + wn * 64 + nt * 16 + lane15;
                C[(size_t)gm * 2048 + gn] = acc[mt][nt][r];
            }
}

// ---------------------------------------------------------------------------
// Fused RoPE + scale + bf16 cast: read Qf/Kf fp32, write Qh (scaled)/Kh bf16.
// ---------------------------------------------------------------------------
__global__ void rope_scale_cast(const float* __restrict__ Qf,
                                const float* __restrict__ Kf,
                                bf16_t* __restrict__ Qh,
                                bf16_t* __restrict__ Kh)
{
    const int idx  = blockIdx.x * 256 + threadIdx.x;   // 1,048,576 total
    const int j4   = (idx & 15) * 4;                   // 0..60
    const int h    = (idx >> 4) & (Hc - 1);
    const int sabs = idx >> 8;
    const int s    = sabs & (Sc - 1);
    const float QS = 0.08838834764831845f;

    const size_t base = (size_t)sabs * HHDc + (size_t)h * HDc + j4;
    float4 q1 = *(const float4*)&Qf[base];
    float4 q2 = *(const float4*)&Qf[base + 64];
    float4 k1 = *(const float4*)&Kf[base];
    float4 k2 = *(const float4*)&Kf[base + 64];

    bf16x4 qo1, qo2, ko1, ko2;
    #pragma unroll
    for (int c = 0; c < 4; ++c) {
        const float freq = expf(-(float)(j4 + c) * 0.14391156514261520f);
        const float ang  = (float)s * freq;
        float sn, cs;
        sincosf(ang, &sn, &cs);
        const float a = ((const float*)&q1)[c], bq = ((const float*)&q2)[c];
        const float x = ((const float*)&k1)[c], y  = ((const float*)&k2)[c];
        qo1[c] = (bf16_t)((a * cs - bq * sn) * QS);
        qo2[c] = (bf16_t)((bq * cs + a * sn) * QS);
        ko1[c] = (bf16_t)(x * cs - y * sn);
        ko2[c] = (bf16_t)(y * cs + x * sn);
    }
    *(bf16x4*)&Qh[base]      = qo1;
    *(bf16x4*)&Qh[base + 64] = qo2;
    *(bf16x4*)&Kh[base]      = ko1;
    *(bf16x4*)&Kh[base + 64] = ko2;
}

// ---------------------------------------------------------------------------
// attn_v7: v6 + SWAPPED QK^T (m214 technique). sc = mfma(A=K_frag, B=Q_frag)
// gives S^T: row(quad*4+r+nt*16)=key, col(lane15)=q. Each thread owns the
// full 64-key row partials for q-row (w*16+lane15):
//   - row-reduce: 15 local fmax + shfl_xor(16,32)  [was 32 shuffles/tile]
//   - P write: 4 x ds_write_b64 (contiguous r)     [was 16 x ds_write_b16]
//   - alpha + denom lane-local -> Arow/Lrow LDS and final barrier deleted
// A/B frags of 16x16x32 share the lane15=index, quad=k-chunk mapping (this
// is how the verified code already reads aq and bk), so the swap is only
// an operand-order change; both LDS reads unchanged. PV unchanged.
// ---------------------------------------------------------------------------
__global__ __launch_bounds__(512, 4) void attn_v7(const bf16_t* __restrict__ Q,
                                                  const bf16_t* __restrict__ K,
                                                  const bf16_t* __restrict__ Vt,
                                                  bf16_t* __restrict__ CTX)
{
    __shared__ bf16_t Ks[64 * 128];    // [k_local][hd]   (col-swizzled)
    __shared__ bf16_t Vts[128 * 64];   // [hd][key_local] (col-swizzled)
    __shared__ bf16_t Ps[128 * 72];    // bf16 P[q][key], wave-private rows

    const int t = threadIdx.x, w = t >> 6, l = t & 63;
    const int lane15 = l & 15, quad = l >> 4;
    const int swr = (lane15 & 7) * 8;          // read-side column swizzle
    const int q0 = blockIdx.x * 128;
    const int b = blockIdx.y >> 4, h = blockIdx.y & 15;
    const size_t qbase = ((size_t)(b * Sc + q0)) * HHDc + h * HDc;
    const size_t vtb   = (size_t)blockIdx.y * HDc * Sc;
    const size_t kb0   = ((size_t)(b * Sc)) * HHDc + h * HDc;

    // ---- Q fragments straight to registers (wave owns 16 q-rows) ----
    bf16x8 qf[4];
    #pragma unroll
    for (int ks = 0; ks < 4; ++ks)
        qf[ks] = *(const bf16x8*)&Q[qbase
            + (size_t)(w * 16 + lane15) * HHDc + (ks * 4 + quad) * 8];

    // online-softmax state for q-row (w*16+lane15), replicated across quads
    float m_ = -INFINITY, l_ = 0.f;

    f32x4 O[8];        // PV acc: O[ht], hd=ht*16+quad*4+c, q=w*16+lane15
    #pragma unroll
    for (int i = 0; i < 8; ++i)
        #pragma unroll
        for (int c = 0; c < 4; ++c) O[i][c] = 0.f;

    // staging geometry (per thread)
    const int krow0 = w * 4 + (l >> 4);      // + p*32 ; K row (key index)
    const int kgc   = lane15 * 8;            // K global col (linear)
    const int vrow0 = w * 8 + (l >> 3);      // + p*64 ; Vt row (hd index)
    const int vgc   = (l & 7) * 8;           // Vt global col within tile

    bf16x8 kst[2], vst[2];
    // prologue: load tile 0 into registers
    #pragma unroll
    for (int p = 0; p < 2; ++p) {
        kst[p] = *(const bf16x8*)&K[kb0 + (size_t)(p * 32 + krow0) * HHDc + kgc];
        vst[p] = *(const bf16x8*)&Vt[vtb + (size_t)(p * 64 + vrow0) * Sc + vgc];
    }

    for (int kt = 0; kt < Sc / 64; ++kt) {
        __syncthreads();   // prev tile's readers done; Ks/Vts free
        // ---- write staged regs to LDS with swizzled column ----
        #pragma unroll
        for (int p = 0; p < 2; ++p) {
            const int rk = p * 32 + krow0;
            *(bf16x8*)&Ks[rk * 128 + (kgc ^ ((rk & 7) * 8))] = kst[p];
        }
        #pragma unroll
        for (int p = 0; p < 2; ++p) {
            const int rv = p * 64 + vrow0;
            *(bf16x8*)&Vts[rv * 64 + (vgc ^ ((rv & 7) * 8))] = vst[p];
        }
        // ---- issue next tile's global loads (hidden under compute) ----
        if (kt + 1 < Sc / 64) {
            const size_t kbn = kb0 + (size_t)(kt + 1) * 64 * HHDc;
            #pragma unroll
            for (int p = 0; p < 2; ++p) {
                kst[p] = *(const bf16x8*)&K[kbn + (size_t)(p * 32 + krow0) * HHDc + kgc];
                vst[p] = *(const bf16x8*)&Vt[vtb + (size_t)(p * 64 + vrow0) * Sc
                                             + (kt + 1) * 64 + vgc];
            }
        }
        __syncthreads();   // Ks/Vts ready for all waves

        // ---- swapped MFMA QK^T: sc[nt][r] = S[key=nt*16+quad*4+r][q=lane15] ----
        f32x4 sc[4];
        #pragma unroll
        for (int j = 0; j < 4; ++j)
            #pragma unroll
            for (int c = 0; c < 4; ++c) sc[j][c] = 0.f;
        __builtin_amdgcn_s_setprio(1);
        #pragma unroll
        for (int ks = 0; ks < 4; ++ks) {
            const int rc = ((ks * 4 + quad) * 8) ^ swr;   // swizzled column
            bf16x8 bk[4];
            #pragma unroll
            for (int nt = 0; nt < 4; ++nt)
                bk[nt] = *(const bf16x8*)&Ks[(nt * 16 + lane15) * 128 + rc];
            #pragma unroll
            for (int nt = 0; nt < 4; ++nt)
                sc[nt] = MFMA16(bk[nt], qf[ks], sc[nt]);   // A=K, B=Q
        }
        __builtin_amdgcn_s_setprio(0);

        // ---- in-register online softmax for q-row (w*16+lane15) ----
        {
            float tm = -INFINITY;
            #pragma unroll
            for (int nt = 0; nt < 4; ++nt)
                #pragma unroll
                for (int r = 0; r < 4; ++r) tm = fmaxf(tm, sc[nt][r]);
            tm = fmaxf(tm, __shfl_xor(tm, 16));
            tm = fmaxf(tm, __shfl_xor(tm, 32));
            const float mo = m_;
            const float mn = fmaxf(mo, tm);
            const float al = __expf(mo - mn);
            m_ = mn;
            float ts = 0.f;
            const int prow = (w * 16 + lane15) * 72;
            #pragma unroll
            for (int nt = 0; nt < 4; ++nt) {
                bf16x4 pw;
                #pragma unroll
                for (int r = 0; r < 4; ++r) {
                    const float p = __expf(sc[nt][r] - mn);
                    pw[r] = (bf16_t)p;
                    ts += p;
                }
                *(bf16x4*)&Ps[prow + nt * 16 + quad * 4] = pw;
            }
            ts += __shfl_xor(ts, 16);
            ts += __shfl_xor(ts, 32);
            l_ = l_ * al + ts;

            // ---- rescale O by lane-local alpha (O's q-index is lane15) ----
            #pragma unroll
            for (int ht = 0; ht < 8; ++ht)
                #pragma unroll
                for (int c = 0; c < 4; ++c) O[ht][c] *= al;
        }
        // Ps is wave-private: wave-synchronous exec + lgkmcnt ordering make a
        // block barrier unnecessary before the PV reads below.

        // ---- MFMA PV: ctx^T += V^T P^T ----
        __builtin_amdgcn_s_setprio(1);
        #pragma unroll
        for (int ks = 0; ks < 2; ++ks) {
            const int rcp = (ks * 4 + quad) * 8;          // Ps: NOT swizzled
            const int rcv = rcp ^ swr;                    // Vts: swizzled
            bf16x8 av[8];
            #pragma unroll
            for (int ht = 0; ht < 8; ++ht)
                av[ht] = *(const bf16x8*)&Vts[(ht * 16 + lane15) * 64 + rcv];
            bf16x8 bp = *(const bf16x8*)&Ps[(w * 16 + lane15) * 72 + rcp];
            #pragma unroll
            for (int ht = 0; ht < 8; ++ht)
                O[ht] = MFMA16(av[ht], bp, O[ht]);
        }
        __builtin_amdgcn_s_setprio(0);
    }

    // ---- write out (denominator is lane-local; no LDS, no barrier) ----
    {
        const float linv = 1.0f / l_;
        const int s = q0 + w * 16 + lane15;
        #pragma unroll
        for (int ht = 0; ht < 8; ++ht) {
            bf16x4 o;
            #pragma unroll
            for (int c = 0; c < 4; ++c) o[c] = (bf16_t)(O[ht][c] * linv);
            *(bf16x4*)&CTX[((size_t)(b * Sc + s)) * HHDc + h * HDc + ht * 16 + quad * 4] = o;
        }
    }
}

// ---------------------------------------------------------------------------
// ws layout (bf16 element offsets; total exactly 134,217,728 B):
//   xb  bf16 [0,        8388608)   -> Kh after qkv_gemm (xb dead)
//   WT3 bf16 [8388608,  20971520)  -> Qh after qkv_gemm (WT3 dead)
//   WoT bf16 [20971520, 25165824)  (alive until final gemm)
//   Qf  fp32 [25165824, 41943040)  -> Vt after rope_scale_cast (Qf dead)
//   Kf  fp32 [41943040, 58720256)  -> CTX after rope_scale_cast (Kf dead)
//   Vb  bf16 [58720256, 67108864)
// ---------------------------------------------------------------------------
extern "C" void kernel_launch(void* const* d_in, const int* in_sizes, int n_in,
                              void* d_out, int out_size, void* d_ws, size_t ws_size,
                              hipStream_t stream)
{
    const float* x  = (const float*)d_in[0];
    const float* Wq = (const float*)d_in[2];
    const float* Wk = (const float*)d_in[3];
    const float* Wv = (const float*)d_in[4];
    const float* Wo = (const float*)d_in[5];
    float* out = (float*)d_out;

    bf16_t* W0  = (bf16_t*)d_ws;
    bf16_t* xb  = W0;
    bf16_t* WT3 = W0 + 8388608;
    bf16_t* WoT = W0 + 20971520;
    float*  Qf  = (float*)(W0 + 25165824);
    float*  Kf  = (float*)(W0 + 41943040);
    bf16_t* Vb  = W0 + 58720256;
    bf16_t* Kh  = W0;                     // alias: xb dead after qkv_gemm
    bf16_t* Qh  = W0 + 8388608;           // alias: WT3 dead after qkv_gemm
    bf16_t* Vt  = W0 + 25165824;          // alias: Qf dead after rope_scale_cast
    bf16_t* CTX = W0 + 41943040;          // alias: Kf dead after rope_scale_cast

    dim3 tw(32, 32);

    convert_x<<<8192, 256, 0, stream>>>(x, xb);
    transpose_w<<<tw, 256, 0, stream>>>(Wq, WT3);
    transpose_w<<<tw, 256, 0, stream>>>(Wk, WT3 + 4194304);
    transpose_w<<<tw, 256, 0, stream>>>(Wv, WT3 + 8388608);
    transpose_w<<<tw, 256, 0, stream>>>(Wo, WoT);

    qkv_gemm<<<dim3(48, 32), 256, 0, stream>>>(xb, WT3, Qf, Kf, Vb);

    rope_scale_cast<<<4096, 256, 0, stream>>>(Qf, Kf, Qh, Kh);
    prep_vtb<<<dim3(32, 2, 32), 256, 0, stream>>>(Vb, Vt);

    attn_v7<<<dim3(16, 32), 512, 0, stream>>>(Qh, Kh, Vt, CTX);

    gemm_bt<<<dim3(16, 32), 256, 0, stream>>>(CTX, WoT, out);
}

// Round 6
// 426.206 us; speedup vs baseline: 1.5055x; 1.0354x over previous
//
#include <hip/hip_runtime.h>
#include <math.h>

// (B,S,D,H,HD) = (2,2048,2048,16,128)
#define Bc   2
#define Sc   2048
#define Dc   2048
#define Hc   16
#define HDc  128
#define BSc  4096
#define HHDc 2048

typedef __bf16 bf16_t;
typedef __bf16 bf16x8 __attribute__((ext_vector_type(8)));
typedef __bf16 bf16x4 __attribute__((ext_vector_type(4)));
typedef float  f32x4  __attribute__((ext_vector_type(4)));

#define AS1(p) ((const __attribute__((address_space(1))) void*)(p))
#define AS3(p) ((__attribute__((address_space(3))) void*)(p))

#define MFMA16(a,b,c) __builtin_amdgcn_mfma_f32_16x16x32_bf16((a),(b),(c),0,0,0)

// ---------------------------------------------------------------------------
// x: fp32 -> bf16 (same layout)  [verified]
// ---------------------------------------------------------------------------
__global__ void convert_x(const float* __restrict__ x, bf16_t* __restrict__ xb)
{
    const size_t i = ((size_t)blockIdx.x * 256 + threadIdx.x) * 4;
    float4 v = *(const float4*)&x[i];
    bf16x4 o; o[0]=(bf16_t)v.x; o[1]=(bf16_t)v.y; o[2]=(bf16_t)v.z; o[3]=(bf16_t)v.w;
    *(bf16x4*)&xb[i] = o;
}

// ---------------------------------------------------------------------------
// W [K=2048][N=2048] fp32 -> W^T [N][K] bf16  [verified]
// ---------------------------------------------------------------------------
__global__ __launch_bounds__(256) void transpose_w(const float* __restrict__ in,
                                                   bf16_t* __restrict__ out)
{
    __shared__ float T[64][65];
    const int t = threadIdx.x;
    const int r0 = blockIdx.y * 64, c0 = blockIdx.x * 64;
    #pragma unroll
    for (int i = 0; i < 4; ++i) {
        int row = i * 16 + (t >> 4);
        int c4  = (t & 15) * 4;
        float4 v = *(const float4*)&in[(size_t)(r0 + row) * 2048 + c0 + c4];
        T[row][c4] = v.x; T[row][c4+1] = v.y; T[row][c4+2] = v.z; T[row][c4+3] = v.w;
    }
    __syncthreads();
    #pragma unroll
    for (int i = 0; i < 4; ++i) {
        int orow = i * 16 + (t >> 4);
        int c4   = (t & 15) * 4;
        bf16x4 o;
        #pragma unroll
        for (int j = 0; j < 4; ++j) o[j] = (bf16_t)T[c4 + j][orow];
        *(bf16x4*)&out[(size_t)(c0 + orow) * 2048 + r0 + c4] = o;
    }
}

// ---------------------------------------------------------------------------
// RoPE cos/sin table: tab[(s*64+j)*2] = cos(s*freq_j), [..+1] = sin.
// Same expf/sincosf arithmetic as the old per-element path (values identical).
// Lives in d_out (dead until final gemm overwrites it).
// ---------------------------------------------------------------------------
__global__ void rope_tab(float* __restrict__ tab)
{
    const int i = blockIdx.x * 256 + threadIdx.x;   // 131072 = s*64 + j
    const int j = i & 63, s = i >> 6;
    const float freq = expf(-(float)j * 0.14391156514261520f);
    float sn, cs;
    sincosf((float)s * freq, &sn, &cs);
    float2 v; v.x = cs; v.y = sn;
    *(float2*)&tab[i * 2] = v;
}

// ---------------------------------------------------------------------------
// Fused QKV GEMM: C[4096][6144] = xb * WT3^T; T2-swizzled LDS (conflicts=0,
// R5-verified). NO XCD remap: default dispatch gives each XCD a fixed 6-col
// B slice (3MB, L2-resident) -- R5 showed remapping tripled FETCH_SIZE.
// Output router: n<2048 -> Qf fp32; n<4096 -> Kf fp32;
//                else -> Vt bf16 TRANSPOSED [bh][hd][s] (fuses old prep_vtb).
// ---------------------------------------------------------------------------
__global__ __launch_bounds__(256) void qkv_gemm(const bf16_t* __restrict__ A,
                                                const bf16_t* __restrict__ Bt,
                                                float* __restrict__ Qf,
                                                float* __restrict__ Kf,
                                                bf16_t* __restrict__ Vt)
{
    __shared__ bf16_t As[128 * 64];
    __shared__ bf16_t Bs[128 * 64];
    const int t = threadIdx.x;
    const int w = t >> 6, l = t & 63;
    const int wm = w >> 1, wn = w & 1;
    const int lane15 = l & 15, quad = l >> 4;
    const int swr = (lane15 & 7) * 8;        // read-side column swizzle
    const int m0 = blockIdx.y * 128, n0 = blockIdx.x * 128;

    f32x4 acc[4][4];
    #pragma unroll
    for (int i = 0; i < 4; ++i)
        #pragma unroll
        for (int j = 0; j < 4; ++j)
            #pragma unroll
            for (int c = 0; c < 4; ++c) acc[i][j][c] = 0.f;

    const int srow = w * 8 + (l >> 3);
    const int gk   = ((l & 7) * 8) ^ ((srow & 7) * 8);   // inverse-swizzled src col

    for (int k0 = 0; k0 < 2048; k0 += 64) {
        __syncthreads();
        #pragma unroll
        for (int p = 0; p < 4; ++p) {
            __builtin_amdgcn_global_load_lds(
                AS1(A + (size_t)(m0 + p * 32 + srow) * 2048 + k0 + gk),
                AS3(&As[(p * 32 + w * 8) * 64]), 16, 0, 0);
            __builtin_amdgcn_global_load_lds(
                AS1(Bt + (size_t)(n0 + p * 32 + srow) * 2048 + k0 + gk),
                AS3(&Bs[(p * 32 + w * 8) * 64]), 16, 0, 0);
        }
        __syncthreads();
        #pragma unroll
        for (int ks = 0; ks < 2; ++ks) {
            const int rc = ((ks * 4 + quad) * 8) ^ swr;
            bf16x8 a[4], b[4];
            #pragma unroll
            for (int mt = 0; mt < 4; ++mt)
                a[mt] = *(const bf16x8*)&As[(wm * 64 + mt * 16 + lane15) * 64 + rc];
            #pragma unroll
            for (int nt = 0; nt < 4; ++nt)
                b[nt] = *(const bf16x8*)&Bs[(wn * 64 + nt * 16 + lane15) * 64 + rc];
            #pragma unroll
            for (int mt = 0; mt < 4; ++mt)
                #pragma unroll
                for (int nt = 0; nt < 4; ++nt)
                    acc[mt][nt] = MFMA16(a[mt], b[nt], acc[mt][nt]);
        }
    }

    if (n0 < 4096) {
        float* __restrict__ dst = (n0 < 2048) ? Qf : Kf;
        const int nb = n0 & 2047;
        #pragma unroll
        for (int mt = 0; mt < 4; ++mt)
            #pragma unroll
            for (int nt = 0; nt < 4; ++nt)
                #pragma unroll
                for (int r = 0; r < 4; ++r) {
                    const int gm = m0 + wm * 64 + mt * 16 + quad * 4 + r;
                    const int gn = nb + wn * 64 + nt * 16 + lane15;
                    dst[(size_t)gm * 2048 + gn] = acc[mt][nt][r];
                }
    } else {
        // V epilogue: write transposed Vt[bh][hd][s]; r = consecutive s.
        const int nb = n0 - 4096;
        #pragma unroll
        for (int mt = 0; mt < 4; ++mt) {
            const int gm = m0 + wm * 64 + mt * 16 + quad * 4;   // +r, 4 consec s
            const int bq = gm >> 11;          // batch (gm..gm+3 same batch)
            const int s  = gm & 2047;
            #pragma unroll
            for (int nt = 0; nt < 4; ++nt) {
                const int gn = nb + wn * 64 + nt * 16 + lane15;
                const int h  = gn >> 7, hd = gn & 127;
                bf16x4 o;
                #pragma unroll
                for (int r = 0; r < 4; ++r) o[r] = (bf16_t)acc[mt][nt][r];
                *(bf16x4*)&Vt[((size_t)((bq * Hc + h) * HDc + hd)) * Sc + s] = o;
            }
        }
    }
}

// ---------------------------------------------------------------------------
// GEMM: C[4096][2048] = A * Bt^T (final proj) + T2 swizzle (no XCD remap)
// ---------------------------------------------------------------------------
__global__ __launch_bounds__(256) void gemm_bt(const bf16_t* __restrict__ A,
                                               const bf16_t* __restrict__ Bt,
                                               float* __restrict__ C)
{
    __shared__ bf16_t As[128 * 64];
    __shared__ bf16_t Bs[128 * 64];
    const int t = threadIdx.x;
    const int w = t >> 6, l = t & 63;
    const int wm = w >> 1, wn = w & 1;
    const int lane15 = l & 15, quad = l >> 4;
    const int swr = (lane15 & 7) * 8;
    const int m0 = blockIdx.y * 128, n0 = blockIdx.x * 128;

    f32x4 acc[4][4];
    #pragma unroll
    for (int i = 0; i < 4; ++i)
        #pragma unroll
        for (int j = 0; j < 4; ++j)
            #pragma unroll
            for (int c = 0; c < 4; ++c) acc[i][j][c] = 0.f;

    const int srow = w * 8 + (l >> 3);
    const int gk   = ((l & 7) * 8) ^ ((srow & 7) * 8);

    for (int k0 = 0; k0 < 2048; k0 += 64) {
        __syncthreads();
        #pragma unroll
        for (int p = 0; p < 4; ++p) {
            __builtin_amdgcn_global_load_lds(
                AS1(A + (size_t)(m0 + p * 32 + srow) * 2048 + k0 + gk),
                AS3(&As[(p * 32 + w * 8) * 64]), 16, 0, 0);
            __builtin_amdgcn_global_load_lds(
                AS1(Bt + (size_t)(n0 + p * 32 + srow) * 2048 + k0 + gk),
                AS3(&Bs[(p * 32 + w * 8) * 64]), 16, 0, 0);
        }
        __syncthreads();
        #pragma unroll
        for (int ks = 0; ks < 2; ++ks) {
            const int rc = ((ks * 4 + quad) * 8) ^ swr;
            bf16x8 a[4], b[4];
            #pragma unroll
            for (int mt = 0; mt < 4; ++mt)
                a[mt] = *(const bf16x8*)&As[(wm * 64 + mt * 16 + lane15) * 64 + rc];
            #pragma unroll
            for (int nt = 0; nt < 4; ++nt)
                b[nt] = *(const bf16x8*)&Bs[(wn * 64 + nt * 16 + lane15) * 64 + rc];
            #pragma unroll
            for (int mt = 0; mt < 4; ++mt)
                #pragma unroll
                for (int nt = 0; nt < 4; ++nt)
                    acc[mt][nt] = MFMA16(a[mt], b[nt], acc[mt][nt]);
        }
    }

    #pragma unroll
    for (int mt = 0; mt < 4; ++mt)
        #pragma unroll
        for (int nt = 0; nt < 4; ++nt)
            #pragma unroll
            for (int r = 0; r < 4; ++r) {
                const int gm = m0 + wm * 64 + mt * 16 + quad * 4 + r;
                const int gn = n0 + wn * 64 + nt * 16 + lane15;
                C[(size_t)gm * 2048 + gn] = acc[mt][nt][r];
            }
}

// ---------------------------------------------------------------------------
// Fused RoPE + scale + bf16 cast, table-driven: reads tab[(s*64+j)*2] = cs,sn
// (same values as before -- absmax-preserving), no trig on the hot path.
// ---------------------------------------------------------------------------
__global__ void rope_scale_cast(const float* __restrict__ Qf,
                                const float* __restrict__ Kf,
                                const float* __restrict__ tab,
                                bf16_t* __restrict__ Qh,
                                bf16_t* __restrict__ Kh)
{
    const int idx  = blockIdx.x * 256 + threadIdx.x;   // 1,048,576 total
    const int j4   = (idx & 15) * 4;                   // 0..60
    const int h    = (idx >> 4) & (Hc - 1);
    const int sabs = idx >> 8;
    const int s    = sabs & (Sc - 1);
    const float QS = 0.08838834764831845f;

    const size_t base = (size_t)sabs * HHDc + (size_t)h * HDc + j4;
    float4 q1 = *(const float4*)&Qf[base];
    float4 q2 = *(const float4*)&Qf[base + 64];
    float4 k1 = *(const float4*)&Kf[base];
    float4 k2 = *(const float4*)&Kf[base + 64];
    float4 t0 = *(const float4*)&tab[(s * 64 + j4) * 2];       // cs0,sn0,cs1,sn1
    float4 t1 = *(const float4*)&tab[(s * 64 + j4 + 2) * 2];   // cs2,sn2,cs3,sn3

    bf16x4 qo1, qo2, ko1, ko2;
    #pragma unroll
    for (int c = 0; c < 4; ++c) {
        const float cs = (c < 2) ? ((c & 1) ? t0.z : t0.x) : ((c & 1) ? t1.z : t1.x);
        const float sn = (c < 2) ? ((c & 1) ? t0.w : t0.y) : ((c & 1) ? t1.w : t1.y);
        const float a = ((const float*)&q1)[c], bq = ((const float*)&q2)[c];
        const float x = ((const float*)&k1)[c], y  = ((const float*)&k2)[c];
        qo1[c] = (bf16_t)((a * cs - bq * sn) * QS);
        qo2[c] = (bf16_t)((bq * cs + a * sn) * QS);
        ko1[c] = (bf16_t)(x * cs - y * sn);
        ko2[c] = (bf16_t)(y * cs + x * sn);
    }
    *(bf16x4*)&Qh[base]      = qo1;
    *(bf16x4*)&Qh[base + 64] = qo2;
    *(bf16x4*)&Kh[base]      = ko1;
    *(bf16x4*)&Kh[base + 64] = ko2;
}

// ---------------------------------------------------------------------------
// attn_v7 (R5-verified): swapped QK^T, lane-local softmax, reg-staged K/V.
// ---------------------------------------------------------------------------
__global__ __launch_bounds__(512, 4) void attn_v7(const bf16_t* __restrict__ Q,
                                                  const bf16_t* __restrict__ K,
                                                  const bf16_t* __restrict__ Vt,
                                                  bf16_t* __restrict__ CTX)
{
    __shared__ bf16_t Ks[64 * 128];    // [k_local][hd]   (col-swizzled)
    __shared__ bf16_t Vts[128 * 64];   // [hd][key_local] (col-swizzled)
    __shared__ bf16_t Ps[128 * 72];    // bf16 P[q][key], wave-private rows

    const int t = threadIdx.x, w = t >> 6, l = t & 63;
    const int lane15 = l & 15, quad = l >> 4;
    const int swr = (lane15 & 7) * 8;          // read-side column swizzle
    const int q0 = blockIdx.x * 128;
    const int b = blockIdx.y >> 4, h = blockIdx.y & 15;
    const size_t qbase = ((size_t)(b * Sc + q0)) * HHDc + h * HDc;
    const size_t vtb   = (size_t)blockIdx.y * HDc * Sc;
    const size_t kb0   = ((size_t)(b * Sc)) * HHDc + h * HDc;

    // ---- Q fragments straight to registers (wave owns 16 q-rows) ----
    bf16x8 qf[4];
    #pragma unroll
    for (int ks = 0; ks < 4; ++ks)
        qf[ks] = *(const bf16x8*)&Q[qbase
            + (size_t)(w * 16 + lane15) * HHDc + (ks * 4 + quad) * 8];

    // online-softmax state for q-row (w*16+lane15), replicated across quads
    float m_ = -INFINITY, l_ = 0.f;

    f32x4 O[8];        // PV acc: O[ht], hd=ht*16+quad*4+c, q=w*16+lane15
    #pragma unroll
    for (int i = 0; i < 8; ++i)
        #pragma unroll
        for (int c = 0; c < 4; ++c) O[i][c] = 0.f;

    // staging geometry (per thread)
    const int krow0 = w * 4 + (l >> 4);      // + p*32 ; K row (key index)
    const int kgc   = lane15 * 8;            // K global col (linear)
    const int vrow0 = w * 8 + (l >> 3);      // + p*64 ; Vt row (hd index)
    const int vgc   = (l & 7) * 8;           // Vt global col within tile

    bf16x8 kst[2], vst[2];
    // prologue: load tile 0 into registers
    #pragma unroll
    for (int p = 0; p < 2; ++p) {
        kst[p] = *(const bf16x8*)&K[kb0 + (size_t)(p * 32 + krow0) * HHDc + kgc];
        vst[p] = *(const bf16x8*)&Vt[vtb + (size_t)(p * 64 + vrow0) * Sc + vgc];
    }

    for (int kt = 0; kt < Sc / 64; ++kt) {
        __syncthreads();   // prev tile's readers done; Ks/Vts free
        // ---- write staged regs to LDS with swizzled column ----
        #pragma unroll
        for (int p = 0; p < 2; ++p) {
            const int rk = p * 32 + krow0;
            *(bf16x8*)&Ks[rk * 128 + (kgc ^ ((rk & 7) * 8))] = kst[p];
        }
        #pragma unroll
        for (int p = 0; p < 2; ++p) {
            const int rv = p * 64 + vrow0;
            *(bf16x8*)&Vts[rv * 64 + (vgc ^ ((rv & 7) * 8))] = vst[p];
        }
        // ---- issue next tile's global loads (hidden under compute) ----
        if (kt + 1 < Sc / 64) {
            const size_t kbn = kb0 + (size_t)(kt + 1) * 64 * HHDc;
            #pragma unroll
            for (int p = 0; p < 2; ++p) {
                kst[p] = *(const bf16x8*)&K[kbn + (size_t)(p * 32 + krow0) * HHDc + kgc];
                vst[p] = *(const bf16x8*)&Vt[vtb + (size_t)(p * 64 + vrow0) * Sc
                                             + (kt + 1) * 64 + vgc];
            }
        }
        __syncthreads();   // Ks/Vts ready for all waves

        // ---- swapped MFMA QK^T: sc[nt][r] = S[key=nt*16+quad*4+r][q=lane15] ----
        f32x4 sc[4];
        #pragma unroll
        for (int j = 0; j < 4; ++j)
            #pragma unroll
            for (int c = 0; c < 4; ++c) sc[j][c] = 0.f;
        __builtin_amdgcn_s_setprio(1);
        #pragma unroll
        for (int ks = 0; ks < 4; ++ks) {
            const int rc = ((ks * 4 + quad) * 8) ^ swr;   // swizzled column
            bf16x8 bk[4];
            #pragma unroll
            for (int nt = 0; nt < 4; ++nt)
                bk[nt] = *(const bf16x8*)&Ks[(nt * 16 + lane15) * 128 + rc];
            #pragma unroll
            for (int nt = 0; nt < 4; ++nt)
                sc[nt] = MFMA16(bk[nt], qf[ks], sc[nt]);   // A=K, B=Q
        }
        __builtin_amdgcn_s_setprio(0);

        // ---- in-register online softmax for q-row (w*16+lane15) ----
        {
            float tm = -INFINITY;
            #pragma unroll
            for (int nt = 0; nt < 4; ++nt)
                #pragma unroll
                for (int r = 0; r < 4; ++r) tm = fmaxf(tm, sc[nt][r]);
            tm = fmaxf(tm, __shfl_xor(tm, 16));
            tm = fmaxf(tm, __shfl_xor(tm, 32));
            const float mo = m_;
            const float mn = fmaxf(mo, tm);
            const float al = __expf(mo - mn);
            m_ = mn;
            float ts = 0.f;
            const int prow = (w * 16 + lane15) * 72;
            #pragma unroll
            for (int nt = 0; nt < 4; ++nt) {
                bf16x4 pw;
                #pragma unroll
                for (int r = 0; r < 4; ++r) {
                    const float p = __expf(sc[nt][r] - mn);
                    pw[r] = (bf16_t)p;
                    ts += p;
                }
                *(bf16x4*)&Ps[prow + nt * 16 + quad * 4] = pw;
            }
            ts += __shfl_xor(ts, 16);
            ts += __shfl_xor(ts, 32);
            l_ = l_ * al + ts;

            // ---- rescale O by lane-local alpha (O's q-index is lane15) ----
            #pragma unroll
            for (int ht = 0; ht < 8; ++ht)
                #pragma unroll
                for (int c = 0; c < 4; ++c) O[ht][c] *= al;
        }
        // Ps is wave-private: wave-synchronous exec + lgkmcnt ordering make a
        // block barrier unnecessary before the PV reads below.

        // ---- MFMA PV: ctx^T += V^T P^T ----
        __builtin_amdgcn_s_setprio(1);
        #pragma unroll
        for (int ks = 0; ks < 2; ++ks) {
            const int rcp = (ks * 4 + quad) * 8;          // Ps: NOT swizzled
            const int rcv = rcp ^ swr;                    // Vts: swizzled
            bf16x8 av[8];
            #pragma unroll
            for (int ht = 0; ht < 8; ++ht)
                av[ht] = *(const bf16x8*)&Vts[(ht * 16 + lane15) * 64 + rcv];
            bf16x8 bp = *(const bf16x8*)&Ps[(w * 16 + lane15) * 72 + rcp];
            #pragma unroll
            for (int ht = 0; ht < 8; ++ht)
                O[ht] = MFMA16(av[ht], bp, O[ht]);
        }
        __builtin_amdgcn_s_setprio(0);
    }

    // ---- write out (denominator is lane-local; no LDS, no barrier) ----
    {
        const float linv = 1.0f / l_;
        const int s = q0 + w * 16 + lane15;
        #pragma unroll
        for (int ht = 0; ht < 8; ++ht) {
            bf16x4 o;
            #pragma unroll
            for (int c = 0; c < 4; ++c) o[c] = (bf16_t)(O[ht][c] * linv);
            *(bf16x4*)&CTX[((size_t)(b * Sc + s)) * HHDc + h * HDc + ht * 16 + quad * 4] = o;
        }
    }
}

// ---------------------------------------------------------------------------
// ws layout (bf16 element offsets; total exactly 134,217,728 B):
//   xb  bf16 [0,        8388608)   -> Kh after qkv_gemm (xb dead)
//   WT3 bf16 [8388608,  20971520)  -> Qh after qkv_gemm (WT3 dead)
//   WoT bf16 [20971520, 25165824)  (alive until final gemm)
//   Qf  fp32 [25165824, 41943040)  -> CTX after rope_scale_cast (Qf dead)
//   Kf  fp32 [41943040, 58720256)
//   Vt  bf16 [58720256, 67108864)  (written transposed by qkv_gemm)
// RoPE table (1 MB) lives in d_out, overwritten by the final gemm.
// ---------------------------------------------------------------------------
extern "C" void kernel_launch(void* const* d_in, const int* in_sizes, int n_in,
                              void* d_out, int out_size, void* d_ws, size_t ws_size,
                              hipStream_t stream)
{
    const float* x  = (const float*)d_in[0];
    const float* Wq = (const float*)d_in[2];
    const float* Wk = (const float*)d_in[3];
    const float* Wv = (const float*)d_in[4];
    const float* Wo = (const float*)d_in[5];
    float* out = (float*)d_out;

    bf16_t* W0  = (bf16_t*)d_ws;
    bf16_t* xb  = W0;
    bf16_t* WT3 = W0 + 8388608;
    bf16_t* WoT = W0 + 20971520;
    float*  Qf  = (float*)(W0 + 25165824);
    float*  Kf  = (float*)(W0 + 41943040);
    bf16_t* Vt  = W0 + 58720256;
    bf16_t* Kh  = W0;                     // alias: xb dead after qkv_gemm
    bf16_t* Qh  = W0 + 8388608;           // alias: WT3 dead after qkv_gemm
    bf16_t* CTX = W0 + 25165824;          // alias: Qf dead after rope_scale_cast
    float*  tab = out;                    // 1 MB table; out overwritten at end

    dim3 tw(32, 32);

    rope_tab<<<512, 256, 0, stream>>>(tab);
    convert_x<<<8192, 256, 0, stream>>>(x, xb);
    transpose_w<<<tw, 256, 0, stream>>>(Wq, WT3);
    transpose_w<<<tw, 256, 0, stream>>>(Wk, WT3 + 4194304);
    transpose_w<<<tw, 256, 0, stream>>>(Wv, WT3 + 8388608);
    transpose_w<<<tw, 256, 0, stream>>>(Wo, WoT);

    qkv_gemm<<<dim3(48, 32), 256, 0, stream>>>(xb, WT3, Qf, Kf, Vt);

    rope_scale_cast<<<4096, 256, 0, stream>>>(Qf, Kf, tab, Qh, Kh);

    attn_v7<<<dim3(16, 32), 512, 0, stream>>>(Qh, Kh, Vt, CTX);

    gemm_bt<<<dim3(16, 32), 256, 0, stream>>>(CTX, WoT, out);
}